// Round 21
// baseline (1555.273 us; speedup 1.0000x reference)
//
#include <hip/hip_runtime.h>
#include <math.h>

// ---------------- constants from the reference ----------------
constexpr int IN_F  = 64;
constexpr int HID_F = 64;
constexpr int OUT_F = 32;
constexpr int NEXP  = 8;
constexpr int EMB   = 64;   // emb_dim

// Encoder is linear: h2 = A^(A^(X W12)) + t*(b1 W2) + b2, W12 = W1@W2.
// CSR build is TWO-PHASE: (1) wave-compaction bucket append by dst-range
// (coalesced writes, no amplification); (2) shard-pinned scatter reading only
// the shard's own 1.6MB bucket -> csr slice + cursor stay L2-resident with no
// streaming evictor (r20: full-stream sharded scatter still 10x write-amp).
// Bucket buffer aliases Ys (dead until encoder).
// Distortion: edges sorted by (d-quarter, s), XCD-pinned, quarter-wave/edge.

// ---------------- utility kernels ----------------
__global__ void zero_f32_kernel(float* __restrict__ p, long long n) {
    long long i = (long long)blockIdx.x * blockDim.x + threadIdx.x;
    long long stride = (long long)gridDim.x * blockDim.x;
    for (; i < n; i += stride) p[i] = 0.0f;
}

__global__ void zero_i32_kernel(int* __restrict__ p, long long n) {
    long long i = (long long)blockIdx.x * blockDim.x + threadIdx.x;
    long long stride = (long long)gridDim.x * blockDim.x;
    for (; i < n; i += stride) p[i] = 0;
}

// ---------------- W12 = W1@W2, c1 = b1@W2 (once) ----------------
__global__ __launch_bounds__(1024)
void w12_kernel(const float* __restrict__ W1, const float* __restrict__ W2,
                const float* __restrict__ b1,
                float* __restrict__ W12, float* __restrict__ c1)
{
    __shared__ float sW2[HID_F * OUT_F];
    const int tid = threadIdx.x;
    for (int i = tid; i < HID_F * OUT_F; i += 1024) sW2[i] = W2[i];
    __syncthreads();
    for (int idx = tid; idx < IN_F * OUT_F; idx += 1024) {
        int i = idx >> 5, j = idx & 31;
        float acc = 0.0f;
#pragma unroll
        for (int k = 0; k < HID_F; ++k) acc += W1[i * HID_F + k] * sW2[k * OUT_F + j];
        W12[idx] = acc;
    }
    if (tid < OUT_F) {
        float acc = 0.0f;
#pragma unroll
        for (int k = 0; k < HID_F; ++k) acc += b1[k] * sW2[k * OUT_F + tid];
        c1[tid] = acc;
    }
}

// ---------------- fused CSR build over both graphs ----------------
__global__ void hist2_kernel(const int* __restrict__ ei0, const int* __restrict__ ei1,
                             int* __restrict__ counts, int E, int N)
{
    int e = blockIdx.x * blockDim.x + threadIdx.x;
    if (e >= 2 * E) return;
    int d = (e < E) ? ei0[E + e] : (ei1[E + (e - E)] + N);
    atomicAdd(&counts[d], 1);
}

// two-level exclusive scan (race-free)
__global__ __launch_bounds__(1024)
void scan1_kernel(const int* __restrict__ counts, int* __restrict__ lexcl,
                  int* __restrict__ partials, int N)
{
    __shared__ int wsum[16];
    const int tid  = threadIdx.x;
    const int lane = tid & 63;
    const int wv   = tid >> 6;
    const int i    = blockIdx.x * 1024 + tid;

    int v = (i < N) ? counts[i] : 0;
    int x = v;
#pragma unroll
    for (int off = 1; off < 64; off <<= 1) {
        int t = __shfl_up(x, off);
        if (lane >= off) x += t;
    }
    if (lane == 63) wsum[wv] = x;
    __syncthreads();
    int woff = 0;
    for (int w = 0; w < wv; ++w) woff += wsum[w];
    if (i < N) lexcl[i] = woff + x - v;
    if (tid == 1023) partials[blockIdx.x] = woff + x;
}

__global__ __launch_bounds__(1024)
void scan2_kernel(int* __restrict__ partials, int NB)
{
    __shared__ int wsum[16];
    const int tid  = threadIdx.x;
    const int lane = tid & 63;
    const int wv   = tid >> 6;
    int v = (tid < NB) ? partials[tid] : 0;
    int x = v;
#pragma unroll
    for (int off = 1; off < 64; off <<= 1) {
        int t = __shfl_up(x, off);
        if (lane >= off) x += t;
    }
    if (lane == 63) wsum[wv] = x;
    __syncthreads();
    int woff = 0;
    for (int w = 0; w < wv; ++w) woff += wsum[w];
    if (tid < NB) partials[tid] = woff + x - v;
}

// combine -> offsets/cursor, dinv = rsqrt(deg+1)
__global__ void scan3_kernel(const int* __restrict__ lexcl, const int* __restrict__ partials,
                             const int* __restrict__ counts,
                             int* __restrict__ offsets, int* __restrict__ cursor,
                             float* __restrict__ dinv, int n2, int e2tot)
{
    int i = blockIdx.x * blockDim.x + threadIdx.x;
    if (i >= n2) return;
    int o = lexcl[i] + partials[i >> 10];
    offsets[i] = o;
    cursor[i]  = o;
    dinv[i] = rsqrtf((float)counts[i] + 1.0f);
    if (i == 0) offsets[n2] = e2tot;
}

// ---- phase 1a: per-block LDS histogram over 8 dst-range shards ----
__global__ __launch_bounds__(256)
void shard_hist_kernel(const int* __restrict__ ei0, const int* __restrict__ ei1,
                       int* __restrict__ bCnt, int E, int N, int n2)
{
    __shared__ int h[8];
    if (threadIdx.x < 8) h[threadIdx.x] = 0;
    __syncthreads();
    long long e = (long long)blockIdx.x * blockDim.x + threadIdx.x;
    long long stride = (long long)gridDim.x * blockDim.x;
    const long long e2 = 2LL * E;
    for (; e < e2; e += stride) {
        int d = (e < E) ? ei0[E + e] : (ei1[E + (e - E)] + N);
        int sh = (int)((8LL * d) / n2);
        atomicAdd(&h[sh], 1);
    }
    __syncthreads();
    if (threadIdx.x < 8) atomicAdd(&bCnt[threadIdx.x], h[threadIdx.x]);
}

// scan of the 8 bucket counts
__global__ void scan8_kernel(const int* __restrict__ bCnt, int* __restrict__ bOff,
                             int* __restrict__ bCur)
{
    if (threadIdx.x == 0) {
        int acc = 0;
        for (int i = 0; i < 8; ++i) { bOff[i] = acc; bCur[i] = acc; acc += bCnt[i]; }
        bOff[8] = acc;
    }
}

// ---- phase 1b: wave-compaction append into dst-range buckets ----
__global__ __launch_bounds__(256)
void bucket_append_kernel(const int* __restrict__ ei0, const int* __restrict__ ei1,
                          int* __restrict__ bCur, int2* __restrict__ bucket,
                          int E, int N, int n2)
{
    const int lane = threadIdx.x & 63;
    const long long stride = (long long)gridDim.x * blockDim.x;
    const long long e2 = 2LL * E;
    for (long long bb = (long long)blockIdx.x * blockDim.x; bb < e2; bb += stride) {
        long long e = bb + threadIdx.x;
        bool valid = (e < e2);
        int s = 0, d = 0, sh = -1;
        if (valid) {
            if (e < E) { s = ei0[e];             d = ei0[E + e]; }
            else       { s = ei1[e - E] + N;     d = ei1[E + (e - E)] + N; }
            sh = (int)((8LL * d) / n2);
        }
#pragma unroll
        for (int b = 0; b < 8; ++b) {
            unsigned long long mask = __ballot(valid && sh == b);
            if (mask == 0ull) continue;
            int cnt = __popcll(mask);
            int leader = __ffsll((unsigned long long)mask) - 1;
            int base = 0;
            if (lane == leader) base = atomicAdd(&bCur[b], cnt);
            base = __shfl(base, leader);
            if (valid && sh == b) {
                unsigned long long lt = (lane == 0) ? 0ull
                                       : (~0ull >> (64 - lane));
                int off = __popcll(mask & lt);
                bucket[base + off] = make_int2(d, s);
            }
        }
    }
}

// ---- phase 2: shard-pinned scatter from the shard's own bucket ----
__global__ __launch_bounds__(256)
void scatter_phase2_kernel(const int2* __restrict__ bucket, const int* __restrict__ bOff,
                           int* __restrict__ cursor, int* __restrict__ csr_src)
{
    const int shard   = blockIdx.x & 7;
    const int bid     = blockIdx.x >> 3;
    const int nblocks = gridDim.x >> 3;
    const int j0 = bOff[shard];
    const int j1 = bOff[shard + 1];
    for (int j = j0 + bid * blockDim.x + threadIdx.x; j < j1;
         j += nblocks * blockDim.x) {
        int2 ed = bucket[j];
        int pos = atomicAdd(&cursor[ed.x], 1);
        csr_src[pos] = ed.y;
    }
}

// ---------------- GEMM: Ys = (X @ W12) * dinv over 2N rows ----------------
__global__ __launch_bounds__(256)
void gemm_ys2_kernel(const float* __restrict__ x0, const float* __restrict__ x1,
                     const float* __restrict__ W12, const float* __restrict__ dinv,
                     float* __restrict__ Ys, int N, int n2)
{
    __shared__ float Ws[IN_F * OUT_F];
    __shared__ float xs[8 * IN_F];
    const int tid = threadIdx.x;

    for (int i = tid; i < IN_F * OUT_F; i += 256) Ws[i] = W12[i];
    const int row0 = blockIdx.x * 8;
    for (int i = tid; i < 8 * IN_F; i += 256) {
        int r = i >> 6;
        int rr = row0 + r;
        float v = 0.0f;
        if (rr < n2) {
            v = (rr < N) ? x0[(size_t)rr * IN_F + (i & 63)]
                         : x1[(size_t)(rr - N) * IN_F + (i & 63)];
        }
        xs[i] = v;
    }
    __syncthreads();

    const int r = tid >> 5;
    const int c = tid & 31;
    const int row = row0 + r;
    if (row >= n2) return;

    float acc = 0.0f;
#pragma unroll
    for (int k = 0; k < IN_F; ++k) acc += xs[r * IN_F + k] * Ws[k * OUT_F + c];

    Ys[(size_t)row * OUT_F + c] = acc * dinv[row];
}

// ---------------- CSR gather-aggregate, 32-wide, unroll 8 ----------------
template<int MODE>
__global__ __launch_bounds__(256)
void csr_agg32_kernel(const int* __restrict__ csr_src, const int* __restrict__ offsets,
                      const float* __restrict__ in, const float* __restrict__ dinv,
                      float* __restrict__ sdsum, const float* __restrict__ c1,
                      const float* __restrict__ b2,
                      float* __restrict__ out, int n)
{
    constexpr int F = OUT_F;              // 32
    const int lane = threadIdx.x & 63;
    const int wid  = (blockIdx.x * (blockDim.x >> 6)) + (threadIdx.x >> 6);
    const int sub  = lane >> 5;           // 2 nodes per wave
    const int f    = lane & 31;
    const int node = wid * 2 + sub;
    const int lbase = sub * F;

    const bool valid = (node < n);
    const int nc   = valid ? node : 0;
    const int off0 = offsets[nc];
    const int off1 = valid ? offsets[nc + 1] : off0;

    float acc0 = valid ? in[(size_t)nc * F + f] : 0.0f;   // self term
    float acc1 = 0.0f, acc2 = 0.0f, acc3 = 0.0f;
    float dsum = 0.0f;                                    // MODE 0 only
    for (int k = off0; k < off1; k += F) {
        int nk = off1 - k; if (nk > F) nk = F;
        int sj = (f < nk) ? csr_src[k + f] : 0;
        if (MODE == 0) {
            float dv = dinv[sj];
            dsum += (f < nk) ? dv : 0.0f;
        }
        int t = 0;
        for (; t + 8 <= nk; t += 8) {
            int s0 = __shfl(sj, lbase + t);
            int s1 = __shfl(sj, lbase + t + 1);
            int s2 = __shfl(sj, lbase + t + 2);
            int s3 = __shfl(sj, lbase + t + 3);
            int s4 = __shfl(sj, lbase + t + 4);
            int s5 = __shfl(sj, lbase + t + 5);
            int s6 = __shfl(sj, lbase + t + 6);
            int s7 = __shfl(sj, lbase + t + 7);
            float v0 = in[(size_t)s0 * F + f];
            float v1 = in[(size_t)s1 * F + f];
            float v2 = in[(size_t)s2 * F + f];
            float v3 = in[(size_t)s3 * F + f];
            float v4 = in[(size_t)s4 * F + f];
            float v5 = in[(size_t)s5 * F + f];
            float v6 = in[(size_t)s6 * F + f];
            float v7 = in[(size_t)s7 * F + f];
            acc0 += v0 + v4;
            acc1 += v1 + v5;
            acc2 += v2 + v6;
            acc3 += v3 + v7;
        }
        for (; t < nk; ++t) {
            int s = __shfl(sj, lbase + t);
            acc0 += in[(size_t)s * F + f];
        }
    }
    if (MODE == 0) {
#pragma unroll
        for (int off = 1; off < 32; off <<= 1) dsum += __shfl_xor(dsum, off);
    }
    if (valid) {
        float di = dinv[node];
        float s = (acc0 + acc1) + (acc2 + acc3);
        if (MODE == 0) {
            out[(size_t)node * F + f] = di * di * s;
            if (f == 0) sdsum[node] = dsum;
        } else {
            float t = di * (di + sdsum[node]);
            out[(size_t)node * F + f] = di * s + t * c1[f] + b2[f];
        }
    }
}

// ---------------- mean pool over both graphs (2N nodes -> 2B graphs) ----------------
__global__ void pool_sum2_kernel(const float* __restrict__ h,
                                 const int* __restrict__ bat0, const int* __restrict__ bat1,
                                 float* __restrict__ pooled, float* __restrict__ cnt,
                                 int N, int n2, int B)
{
    int t = blockIdx.x * blockDim.x + threadIdx.x;
    int i = t >> 5;          // node
    int f = t & 31;          // feature
    if (i >= n2) return;
    int g = (i < N) ? bat0[i] : (bat1[i - N] + B);
    atomicAdd(&pooled[(size_t)g * OUT_F + f], h[(size_t)i * OUT_F + f]);
    if (f == 0) atomicAdd(&cnt[g], 1.0f);
}

__global__ void pool_div_kernel(float* __restrict__ pooled, const float* __restrict__ cnt, int B2)
{
    int t = blockIdx.x * blockDim.x + threadIdx.x;
    if (t >= B2 * OUT_F) return;
    int g = t >> 5;
    pooled[t] /= fmaxf(cnt[g], 1.0f);
}

// ---------------- gate: softmax([p0|p1] @ Wc + bc) ----------------
__global__ void gate_kernel(const float* __restrict__ p0, const float* __restrict__ p1,
                            const float* __restrict__ Wc, const float* __restrict__ bc,
                            float* __restrict__ gate, int B)
{
    int g = blockIdx.x * blockDim.x + threadIdx.x;
    if (g >= B) return;
    float xv[2 * OUT_F];
#pragma unroll
    for (int k = 0; k < OUT_F; ++k) xv[k] = p0[(size_t)g * OUT_F + k];
#pragma unroll
    for (int k = 0; k < OUT_F; ++k) xv[OUT_F + k] = p1[(size_t)g * OUT_F + k];

    float lg[NEXP];
    float m = -1e30f;
#pragma unroll
    for (int e = 0; e < NEXP; ++e) {
        float acc = bc[e];
#pragma unroll
        for (int k = 0; k < 2 * OUT_F; ++k) acc += xv[k] * Wc[k * NEXP + e];
        lg[e] = acc;
        m = fmaxf(m, acc);
    }
    float se = 0.0f;
#pragma unroll
    for (int e = 0; e < NEXP; ++e) { lg[e] = expf(lg[e] - m); se += lg[e]; }
    float inv = 1.0f / se;
#pragma unroll
    for (int e = 0; e < NEXP; ++e) gate[(size_t)g * NEXP + e] = lg[e] * inv;
}

__global__ void zero_scalar_kernel(float* p) { *p = 0.0f; }

// ---------------- distortion: sort edges by key = qd*B + s ----------------
__global__ void histK_kernel(const int* __restrict__ s_idx, const int* __restrict__ d_idx,
                             int* __restrict__ histK, int E2, int B, int quarter)
{
    int e = blockIdx.x * blockDim.x + threadIdx.x;
    if (e >= E2) return;
    int qd = d_idx[e] / quarter; if (qd > 3) qd = 3;
    atomicAdd(&histK[qd * B + s_idx[e]], 1);
}

__global__ void combineK_kernel(const int* __restrict__ lexclK, const int* __restrict__ partialsK,
                                int* __restrict__ offK, int* __restrict__ curK, int nk, int E2)
{
    int i = blockIdx.x * blockDim.x + threadIdx.x;
    if (i >= nk) return;
    int o = lexclK[i] + partialsK[i >> 10];
    offK[i] = o;
    curK[i] = o;
    if (i == 0) offK[nk] = E2;
}

__global__ void scatterK_kernel(const int* __restrict__ s_idx, const int* __restrict__ d_idx,
                                const float* __restrict__ dis,
                                int* __restrict__ curK, int* __restrict__ dD,
                                float* __restrict__ disD, int E2, int B, int quarter)
{
    int e = blockIdx.x * blockDim.x + threadIdx.x;
    if (e >= E2) return;
    int d = d_idx[e];
    int qd = d / quarter; if (qd > 3) qd = 3;
    int pos = atomicAdd(&curK[qd * B + s_idx[e]], 1);
    dD[pos] = d;
    disD[pos] = dis[e];
}

// Shard = (qd, s-half) pinned to XCD (blockIdx&7); grid = 1024 blocks.
// QUARTER-WAVE (16 lanes) per edge: lane ql holds float4 ql+16k -> its k-th
// float4 is expert k. 4-round butterfly makes all 8 expert diffs lane-local.
__global__ __launch_bounds__(256)
void distortion6_kernel(const float* __restrict__ emb, const float* __restrict__ gate,
                        const int* __restrict__ offK, const int* __restrict__ dD,
                        const float* __restrict__ disD,
                        float* __restrict__ loss, int B, int E2)
{
    const int lane = threadIdx.x & 63;
    const int q    = lane >> 4;          // quarter (which edge of the 4)
    const int ql   = lane & 15;          // lane within quarter
    const int xcd  = blockIdx.x & 7;
    const int bid  = blockIdx.x >> 3;
    const int wv   = threadIdx.x >> 6;   // 0..3
    const int wIdx = bid * 4 + wv;       // wave index within shard
    const int nws  = (gridDim.x >> 3) * 4; // waves per shard

    const int qd   = xcd >> 1;
    const int sh   = xcd & 1;
    const int halfB = B >> 1;
    const int k0 = qd * B + sh * halfB;
    const int k1 = qd * B + (sh ? B : halfB);

    const float4* emb4  = (const float4*)emb;
    const float4* gate4 = (const float4*)gate;

    float lsum = 0.0f;
    for (int k = k0 + wIdx; k < k1; k += nws) {
        const int j0 = offK[k];
        const int j1 = offK[k + 1];
        if (j0 == j1) continue;
        const int s = k - qd * B;

        const float4* es = emb4 + (size_t)s * 128;
        float4 a0 = es[ql];
        float4 a1 = es[ql + 16];
        float4 a2 = es[ql + 32];
        float4 a3 = es[ql + 48];
        float4 a4 = es[ql + 64];
        float4 a5 = es[ql + 80];
        float4 a6 = es[ql + 96];
        float4 a7 = es[ql + 112];
        float4 gs0 = gate4[(size_t)s * 2];
        float4 gs1 = gate4[(size_t)s * 2 + 1];

        for (int j = j0 + q; j < j1; j += 4) {
            int d = dD[j];
            float dv = disD[j];
            const float4* ed = emb4 + (size_t)d * 128;
            float4 b0 = ed[ql];
            float4 b1 = ed[ql + 16];
            float4 b2 = ed[ql + 32];
            float4 b3 = ed[ql + 48];
            float4 b4 = ed[ql + 64];
            float4 b5 = ed[ql + 80];
            float4 b6 = ed[ql + 96];
            float4 b7 = ed[ql + 112];
            float4 gd0 = gate4[(size_t)d * 2];
            float4 gd1 = gate4[(size_t)d * 2 + 1];

            float p[NEXP];
            float dx;
            dx = a0.x - b0.x; p[0]  = dx * dx;
            dx = a0.y - b0.y; p[0] += dx * dx;
            dx = a0.z - b0.z; p[0] += dx * dx;
            dx = a0.w - b0.w; p[0] += dx * dx;
            dx = a1.x - b1.x; p[1]  = dx * dx;
            dx = a1.y - b1.y; p[1] += dx * dx;
            dx = a1.z - b1.z; p[1] += dx * dx;
            dx = a1.w - b1.w; p[1] += dx * dx;
            dx = a2.x - b2.x; p[2]  = dx * dx;
            dx = a2.y - b2.y; p[2] += dx * dx;
            dx = a2.z - b2.z; p[2] += dx * dx;
            dx = a2.w - b2.w; p[2] += dx * dx;
            dx = a3.x - b3.x; p[3]  = dx * dx;
            dx = a3.y - b3.y; p[3] += dx * dx;
            dx = a3.z - b3.z; p[3] += dx * dx;
            dx = a3.w - b3.w; p[3] += dx * dx;
            dx = a4.x - b4.x; p[4]  = dx * dx;
            dx = a4.y - b4.y; p[4] += dx * dx;
            dx = a4.z - b4.z; p[4] += dx * dx;
            dx = a4.w - b4.w; p[4] += dx * dx;
            dx = a5.x - b5.x; p[5]  = dx * dx;
            dx = a5.y - b5.y; p[5] += dx * dx;
            dx = a5.z - b5.z; p[5] += dx * dx;
            dx = a5.w - b5.w; p[5] += dx * dx;
            dx = a6.x - b6.x; p[6]  = dx * dx;
            dx = a6.y - b6.y; p[6] += dx * dx;
            dx = a6.z - b6.z; p[6] += dx * dx;
            dx = a6.w - b6.w; p[6] += dx * dx;
            dx = a7.x - b7.x; p[7]  = dx * dx;
            dx = a7.y - b7.y; p[7] += dx * dx;
            dx = a7.z - b7.z; p[7] += dx * dx;
            dx = a7.w - b7.w; p[7] += dx * dx;

            // butterfly within the 16-lane quarter -> all lanes hold full sums
#pragma unroll
            for (int off = 1; off < 16; off <<= 1) {
#pragma unroll
                for (int t = 0; t < NEXP; ++t) p[t] += __shfl_xor(p[t], off);
            }

            float gp[NEXP] = { gs0.x * gd0.x, gs0.y * gd0.y, gs0.z * gd0.z, gs0.w * gd0.w,
                               gs1.x * gd1.x, gs1.y * gd1.y, gs1.z * gd1.z, gs1.w * gd1.w };
            float m = gp[0];
#pragma unroll
            for (int t = 1; t < NEXP; ++t) m = fmaxf(m, gp[t]);
            float se = 0.0f;
#pragma unroll
            for (int t = 0; t < NEXP; ++t) { gp[t] = expf(gp[t] - m); se += gp[t]; }
            float dsum = 0.0f;
#pragma unroll
            for (int t = 0; t < NEXP; ++t) dsum += p[t] * gp[t];

            lsum += fabsf((dsum / se) / dv - 1.0f);
        }
    }
    // all 16 lanes of a quarter hold the same lsum; xor 16 then 32 sums quarters
    lsum += __shfl_xor(lsum, 16);
    lsum += __shfl_xor(lsum, 32);
    if (lane == 0) atomicAdd(loss, lsum / (float)E2);
}

// ---------------- launch ----------------
extern "C" void kernel_launch(void* const* d_in, const int* in_sizes, int n_in,
                              void* d_out, int out_size, void* d_ws, size_t ws_size,
                              hipStream_t stream)
{
    const float* x0   = (const float*)d_in[0];
    const float* x1   = (const float*)d_in[1];
    const float* W1   = (const float*)d_in[2];
    const float* b1   = (const float*)d_in[3];
    const float* W2   = (const float*)d_in[4];
    const float* b2   = (const float*)d_in[5];
    const float* Wc   = (const float*)d_in[6];
    const float* bc   = (const float*)d_in[7];
    const float* emb  = (const float*)d_in[8];
    const float* dis  = (const float*)d_in[9];
    const int*   ei0  = (const int*)d_in[10];
    const int*   ei1  = (const int*)d_in[11];
    const int*   bat0 = (const int*)d_in[12];
    const int*   bat1 = (const int*)d_in[13];
    const int*   ei2  = (const int*)d_in[14];

    const int N  = in_sizes[0] / IN_F;
    const int E  = in_sizes[10] / 2;
    const int B  = in_sizes[8] / (NEXP * EMB);
    const int E2 = in_sizes[14] / 2;
    const int n2 = 2 * N;
    const int nk = 4 * B;                          // sort keys
    const int quarter = (B + 3) / 4;

    float* gate_out = (float*)d_out;               // B*NEXP
    float* loss_out = gate_out + (size_t)B * NEXP; // 1

    // workspace layout (floats)
    float* ws      = (float*)d_ws;
    float* dinv    = ws;                           // 2N
    float* Ys      = dinv + n2;                    // 2N*32  (bucket aliases this)
    float* Zs      = Ys + (size_t)n2 * OUT_F;      // 2N*32
    float* sdsum   = Zs + (size_t)n2 * OUT_F;      // 2N
    float* pooled  = sdsum + n2;                   // 2B*32
    float* cnt     = pooled + (size_t)2 * B * OUT_F; // 2B
    float* W12     = cnt + 2 * B;                  // 64*32
    float* c1      = W12 + IN_F * OUT_F;           // 32
    float* disD    = c1 + OUT_F;                   // E2
    int*   iws     = (int*)(disD + E2);
    int*   counts  = iws;                          // 2N
    int*   offsets = counts + n2;                  // 2N+1
    int*   cursor  = offsets + n2 + 1;             // 2N
    int*   csr_src = cursor + n2;                  // 2E
    int*   lexcl   = csr_src + 2 * E;              // 2N
    int*   partials= lexcl + n2;                   // <=1024
    int*   histK   = partials + 1024;              // 4B
    int*   lexclK  = histK + nk;                   // 4B
    int*   partialsK = lexclK + nk;                // <=1024 (16 used)
    int*   offK    = partialsK + 1024;             // 4B+1
    int*   curK    = offK + nk + 1;                // 4B
    int*   dD      = curK + nk;                    // E2
    int*   bCnt    = dD + E2;                      // 8
    int*   bOff    = bCnt + 8;                     // 9
    int*   bCur    = bOff + 9;                     // 8
    int2*  bucket  = (int2*)Ys;                    // 2E int2 (12.8MB, aliases Ys)

    const int TB = 256;
    const int zgrid = 512;
    const int NB2 = (n2 + 1023) / 1024;            // scan blocks over 2N
    const int NBK = (nk + 1023) / 1024;            // scan blocks over 4B keys

    // W12 = W1@W2, c1 = b1@W2 (once)
    w12_kernel<<<1, 1024, 0, stream>>>(W1, W2, b1, W12, c1);

    // ---- fused CSR build over both graphs (two-phase scatter) ----
    zero_i32_kernel<<<zgrid, TB, 0, stream>>>(counts, n2);
    zero_i32_kernel<<<1, 64, 0, stream>>>(bCnt, 8);
    hist2_kernel<<<(2 * E + TB - 1) / TB, TB, 0, stream>>>(ei0, ei1, counts, E, N);
    scan1_kernel<<<NB2, 1024, 0, stream>>>(counts, lexcl, partials, n2);
    scan2_kernel<<<1, 1024, 0, stream>>>(partials, NB2);
    scan3_kernel<<<(n2 + TB - 1) / TB, TB, 0, stream>>>(lexcl, partials, counts,
                                                        offsets, cursor, dinv, n2, 2 * E);
    shard_hist_kernel<<<512, TB, 0, stream>>>(ei0, ei1, bCnt, E, N, n2);
    scan8_kernel<<<1, 64, 0, stream>>>(bCnt, bOff, bCur);
    bucket_append_kernel<<<512, TB, 0, stream>>>(ei0, ei1, bCur, bucket, E, N, n2);
    scatter_phase2_kernel<<<1024, TB, 0, stream>>>(bucket, bOff, cursor, csr_src);

    // ---- distortion edge sort by key (qd, s) ----
    zero_i32_kernel<<<zgrid, TB, 0, stream>>>(histK, nk);
    histK_kernel<<<(E2 + TB - 1) / TB, TB, 0, stream>>>(ei2, ei2 + E2, histK, E2, B, quarter);
    scan1_kernel<<<NBK, 1024, 0, stream>>>(histK, lexclK, partialsK, nk);
    scan2_kernel<<<1, 1024, 0, stream>>>(partialsK, NBK);
    combineK_kernel<<<(nk + TB - 1) / TB, TB, 0, stream>>>(lexclK, partialsK, offK, curK, nk, E2);
    scatterK_kernel<<<(E2 + TB - 1) / TB, TB, 0, stream>>>(ei2, ei2 + E2, dis,
                                                           curK, dD, disD, E2, B, quarter);

    // ---- encoder: Ys = (X@W12)*dinv ; two aggregation passes ----
    // (gemm overwrites Ys; bucket is dead by now)
    gemm_ys2_kernel<<<(n2 + 7) / 8, 256, 0, stream>>>(x0, x1, W12, dinv, Ys, N, n2);
    csr_agg32_kernel<0><<<(n2 + 7) / 8, TB, 0, stream>>>(csr_src, offsets, Ys, dinv,
                                                         sdsum, nullptr, nullptr, Zs, n2);
    csr_agg32_kernel<1><<<(n2 + 7) / 8, TB, 0, stream>>>(csr_src, offsets, Zs, dinv,
                                                         sdsum, c1, b2, Ys, n2);

    // ---- mean pool (both graphs) ----
    zero_f32_kernel<<<zgrid, TB, 0, stream>>>(pooled, (long long)2 * B * OUT_F);
    zero_f32_kernel<<<zgrid, TB, 0, stream>>>(cnt, 2 * B);
    pool_sum2_kernel<<<((n2 * 32) + TB - 1) / TB, TB, 0, stream>>>(Ys, bat0, bat1,
                                                                   pooled, cnt, N, n2, B);
    pool_div_kernel<<<((2 * B * OUT_F) + TB - 1) / TB, TB, 0, stream>>>(pooled, cnt, 2 * B);

    // ---- gate ----
    gate_kernel<<<(B + TB - 1) / TB, TB, 0, stream>>>(pooled, pooled + (size_t)B * OUT_F,
                                                      Wc, bc, gate_out, B);

    // ---- distortion loss (XCD-sharded, quarter-wave per edge, 1024 blocks) ----
    zero_scalar_kernel<<<1, 1, 0, stream>>>(loss_out);
    distortion6_kernel<<<1024, TB, 0, stream>>>(emb, gate_out, offK, dD, disD,
                                                loss_out, B, E2);
}

// Round 22
// 408.030 us; speedup vs baseline: 3.8117x; 3.8117x over previous
//
#include <hip/hip_runtime.h>
#include <math.h>

// ---------------- constants from the reference ----------------
constexpr int IN_F  = 64;
constexpr int HID_F = 64;
constexpr int OUT_F = 32;
constexpr int NEXP  = 8;
constexpr int EMB   = 64;   // emb_dim

// Encoder is linear: h2 = A^(A^(X W12)) + t*(b1 W2) + b2, W12 = W1@W2.
// Distortion: edges sorted by key (d-quarter, s); shard pinned to XCD ->
// d-rows L2-resident; quarter-wave per edge. Grid 1024 (4096-wave knee).
// Scatter: dst-range-sharded x8, plain loads (r19 best: 73.6us).
// REVERTED r20 (nt loads: null) and r21 (two-phase bucket: 8-counter global
// atomic serialization, 1140us). r19 = best measured total (407.3us).

// ---------------- utility kernels ----------------
__global__ void zero_f32_kernel(float* __restrict__ p, long long n) {
    long long i = (long long)blockIdx.x * blockDim.x + threadIdx.x;
    long long stride = (long long)gridDim.x * blockDim.x;
    for (; i < n; i += stride) p[i] = 0.0f;
}

__global__ void zero_i32_kernel(int* __restrict__ p, long long n) {
    long long i = (long long)blockIdx.x * blockDim.x + threadIdx.x;
    long long stride = (long long)gridDim.x * blockDim.x;
    for (; i < n; i += stride) p[i] = 0;
}

// ---------------- W12 = W1@W2, c1 = b1@W2 (once) ----------------
__global__ __launch_bounds__(1024)
void w12_kernel(const float* __restrict__ W1, const float* __restrict__ W2,
                const float* __restrict__ b1,
                float* __restrict__ W12, float* __restrict__ c1)
{
    __shared__ float sW2[HID_F * OUT_F];
    const int tid = threadIdx.x;
    for (int i = tid; i < HID_F * OUT_F; i += 1024) sW2[i] = W2[i];
    __syncthreads();
    for (int idx = tid; idx < IN_F * OUT_F; idx += 1024) {
        int i = idx >> 5, j = idx & 31;
        float acc = 0.0f;
#pragma unroll
        for (int k = 0; k < HID_F; ++k) acc += W1[i * HID_F + k] * sW2[k * OUT_F + j];
        W12[idx] = acc;
    }
    if (tid < OUT_F) {
        float acc = 0.0f;
#pragma unroll
        for (int k = 0; k < HID_F; ++k) acc += b1[k] * sW2[k * OUT_F + tid];
        c1[tid] = acc;
    }
}

// ---------------- fused CSR build over both graphs ----------------
__global__ void hist2_kernel(const int* __restrict__ ei0, const int* __restrict__ ei1,
                             int* __restrict__ counts, int E, int N)
{
    int e = blockIdx.x * blockDim.x + threadIdx.x;
    if (e >= 2 * E) return;
    int d = (e < E) ? ei0[E + e] : (ei1[E + (e - E)] + N);
    atomicAdd(&counts[d], 1);
}

// two-level exclusive scan (race-free)
__global__ __launch_bounds__(1024)
void scan1_kernel(const int* __restrict__ counts, int* __restrict__ lexcl,
                  int* __restrict__ partials, int N)
{
    __shared__ int wsum[16];
    const int tid  = threadIdx.x;
    const int lane = tid & 63;
    const int wv   = tid >> 6;
    const int i    = blockIdx.x * 1024 + tid;

    int v = (i < N) ? counts[i] : 0;
    int x = v;
#pragma unroll
    for (int off = 1; off < 64; off <<= 1) {
        int t = __shfl_up(x, off);
        if (lane >= off) x += t;
    }
    if (lane == 63) wsum[wv] = x;
    __syncthreads();
    int woff = 0;
    for (int w = 0; w < wv; ++w) woff += wsum[w];
    if (i < N) lexcl[i] = woff + x - v;
    if (tid == 1023) partials[blockIdx.x] = woff + x;
}

__global__ __launch_bounds__(1024)
void scan2_kernel(int* __restrict__ partials, int NB)
{
    __shared__ int wsum[16];
    const int tid  = threadIdx.x;
    const int lane = tid & 63;
    const int wv   = tid >> 6;
    int v = (tid < NB) ? partials[tid] : 0;
    int x = v;
#pragma unroll
    for (int off = 1; off < 64; off <<= 1) {
        int t = __shfl_up(x, off);
        if (lane >= off) x += t;
    }
    if (lane == 63) wsum[wv] = x;
    __syncthreads();
    int woff = 0;
    for (int w = 0; w < wv; ++w) woff += wsum[w];
    if (tid < NB) partials[tid] = woff + x - v;
}

// combine -> offsets/cursor, dinv = rsqrt(deg+1)
__global__ void scan3_kernel(const int* __restrict__ lexcl, const int* __restrict__ partials,
                             const int* __restrict__ counts,
                             int* __restrict__ offsets, int* __restrict__ cursor,
                             float* __restrict__ dinv, int n2, int e2tot)
{
    int i = blockIdx.x * blockDim.x + threadIdx.x;
    if (i >= n2) return;
    int o = lexcl[i] + partials[i >> 10];
    offsets[i] = o;
    cursor[i]  = o;
    dinv[i] = rsqrtf((float)counts[i] + 1.0f);
    if (i == 0) offsets[n2] = e2tot;
}

// dst-range-sharded scatter (r15-verified; r19 best at 73.6us)
__global__ __launch_bounds__(256)
void scatter2_shard_kernel(const int* __restrict__ ei0, const int* __restrict__ ei1,
                           int* __restrict__ cursor, int* __restrict__ csr_src,
                           int E, int N, int n2)
{
    const int shard   = blockIdx.x & 7;
    const int bid     = blockIdx.x >> 3;
    const int nblocks = gridDim.x >> 3;
    const int lo = (int)(((long long)n2 * shard) >> 3);
    const int hi = (int)(((long long)n2 * (shard + 1)) >> 3);

    long long start  = (long long)bid * blockDim.x + threadIdx.x;
    long long stride = (long long)nblocks * blockDim.x;
    const long long e2 = 2LL * E;
    for (long long e = start; e < e2; e += stride) {
        int s, d;
        if (e < E) { s = ei0[e];                 d = ei0[E + e]; }
        else       { s = ei1[e - E] + N;         d = ei1[E + (e - E)] + N; }
        if (d >= lo && d < hi) {
            int pos = atomicAdd(&cursor[d], 1);
            csr_src[pos] = s;
        }
    }
}

// ---------------- GEMM: Ys = (X @ W12) * dinv over 2N rows ----------------
__global__ __launch_bounds__(256)
void gemm_ys2_kernel(const float* __restrict__ x0, const float* __restrict__ x1,
                     const float* __restrict__ W12, const float* __restrict__ dinv,
                     float* __restrict__ Ys, int N, int n2)
{
    __shared__ float Ws[IN_F * OUT_F];
    __shared__ float xs[8 * IN_F];
    const int tid = threadIdx.x;

    for (int i = tid; i < IN_F * OUT_F; i += 256) Ws[i] = W12[i];
    const int row0 = blockIdx.x * 8;
    for (int i = tid; i < 8 * IN_F; i += 256) {
        int r = i >> 6;
        int rr = row0 + r;
        float v = 0.0f;
        if (rr < n2) {
            v = (rr < N) ? x0[(size_t)rr * IN_F + (i & 63)]
                         : x1[(size_t)(rr - N) * IN_F + (i & 63)];
        }
        xs[i] = v;
    }
    __syncthreads();

    const int r = tid >> 5;
    const int c = tid & 31;
    const int row = row0 + r;
    if (row >= n2) return;

    float acc = 0.0f;
#pragma unroll
    for (int k = 0; k < IN_F; ++k) acc += xs[r * IN_F + k] * Ws[k * OUT_F + c];

    Ys[(size_t)row * OUT_F + c] = acc * dinv[row];
}

// ---------------- CSR gather-aggregate, 32-wide, unroll 8 ----------------
template<int MODE>
__global__ __launch_bounds__(256)
void csr_agg32_kernel(const int* __restrict__ csr_src, const int* __restrict__ offsets,
                      const float* __restrict__ in, const float* __restrict__ dinv,
                      float* __restrict__ sdsum, const float* __restrict__ c1,
                      const float* __restrict__ b2,
                      float* __restrict__ out, int n)
{
    constexpr int F = OUT_F;              // 32
    const int lane = threadIdx.x & 63;
    const int wid  = (blockIdx.x * (blockDim.x >> 6)) + (threadIdx.x >> 6);
    const int sub  = lane >> 5;           // 2 nodes per wave
    const int f    = lane & 31;
    const int node = wid * 2 + sub;
    const int lbase = sub * F;

    const bool valid = (node < n);
    const int nc   = valid ? node : 0;
    const int off0 = offsets[nc];
    const int off1 = valid ? offsets[nc + 1] : off0;

    float acc0 = valid ? in[(size_t)nc * F + f] : 0.0f;   // self term
    float acc1 = 0.0f, acc2 = 0.0f, acc3 = 0.0f;
    float dsum = 0.0f;                                    // MODE 0 only
    for (int k = off0; k < off1; k += F) {
        int nk = off1 - k; if (nk > F) nk = F;
        int sj = (f < nk) ? csr_src[k + f] : 0;
        if (MODE == 0) {
            float dv = dinv[sj];
            dsum += (f < nk) ? dv : 0.0f;
        }
        int t = 0;
        for (; t + 8 <= nk; t += 8) {
            int s0 = __shfl(sj, lbase + t);
            int s1 = __shfl(sj, lbase + t + 1);
            int s2 = __shfl(sj, lbase + t + 2);
            int s3 = __shfl(sj, lbase + t + 3);
            int s4 = __shfl(sj, lbase + t + 4);
            int s5 = __shfl(sj, lbase + t + 5);
            int s6 = __shfl(sj, lbase + t + 6);
            int s7 = __shfl(sj, lbase + t + 7);
            float v0 = in[(size_t)s0 * F + f];
            float v1 = in[(size_t)s1 * F + f];
            float v2 = in[(size_t)s2 * F + f];
            float v3 = in[(size_t)s3 * F + f];
            float v4 = in[(size_t)s4 * F + f];
            float v5 = in[(size_t)s5 * F + f];
            float v6 = in[(size_t)s6 * F + f];
            float v7 = in[(size_t)s7 * F + f];
            acc0 += v0 + v4;
            acc1 += v1 + v5;
            acc2 += v2 + v6;
            acc3 += v3 + v7;
        }
        for (; t < nk; ++t) {
            int s = __shfl(sj, lbase + t);
            acc0 += in[(size_t)s * F + f];
        }
    }
    if (MODE == 0) {
#pragma unroll
        for (int off = 1; off < 32; off <<= 1) dsum += __shfl_xor(dsum, off);
    }
    if (valid) {
        float di = dinv[node];
        float s = (acc0 + acc1) + (acc2 + acc3);
        if (MODE == 0) {
            out[(size_t)node * F + f] = di * di * s;
            if (f == 0) sdsum[node] = dsum;
        } else {
            float t = di * (di + sdsum[node]);
            out[(size_t)node * F + f] = di * s + t * c1[f] + b2[f];
        }
    }
}

// ---------------- mean pool over both graphs (2N nodes -> 2B graphs) ----------------
__global__ void pool_sum2_kernel(const float* __restrict__ h,
                                 const int* __restrict__ bat0, const int* __restrict__ bat1,
                                 float* __restrict__ pooled, float* __restrict__ cnt,
                                 int N, int n2, int B)
{
    int t = blockIdx.x * blockDim.x + threadIdx.x;
    int i = t >> 5;          // node
    int f = t & 31;          // feature
    if (i >= n2) return;
    int g = (i < N) ? bat0[i] : (bat1[i - N] + B);
    atomicAdd(&pooled[(size_t)g * OUT_F + f], h[(size_t)i * OUT_F + f]);
    if (f == 0) atomicAdd(&cnt[g], 1.0f);
}

__global__ void pool_div_kernel(float* __restrict__ pooled, const float* __restrict__ cnt, int B2)
{
    int t = blockIdx.x * blockDim.x + threadIdx.x;
    if (t >= B2 * OUT_F) return;
    int g = t >> 5;
    pooled[t] /= fmaxf(cnt[g], 1.0f);
}

// ---------------- gate: softmax([p0|p1] @ Wc + bc) ----------------
__global__ void gate_kernel(const float* __restrict__ p0, const float* __restrict__ p1,
                            const float* __restrict__ Wc, const float* __restrict__ bc,
                            float* __restrict__ gate, int B)
{
    int g = blockIdx.x * blockDim.x + threadIdx.x;
    if (g >= B) return;
    float xv[2 * OUT_F];
#pragma unroll
    for (int k = 0; k < OUT_F; ++k) xv[k] = p0[(size_t)g * OUT_F + k];
#pragma unroll
    for (int k = 0; k < OUT_F; ++k) xv[OUT_F + k] = p1[(size_t)g * OUT_F + k];

    float lg[NEXP];
    float m = -1e30f;
#pragma unroll
    for (int e = 0; e < NEXP; ++e) {
        float acc = bc[e];
#pragma unroll
        for (int k = 0; k < 2 * OUT_F; ++k) acc += xv[k] * Wc[k * NEXP + e];
        lg[e] = acc;
        m = fmaxf(m, acc);
    }
    float se = 0.0f;
#pragma unroll
    for (int e = 0; e < NEXP; ++e) { lg[e] = expf(lg[e] - m); se += lg[e]; }
    float inv = 1.0f / se;
#pragma unroll
    for (int e = 0; e < NEXP; ++e) gate[(size_t)g * NEXP + e] = lg[e] * inv;
}

__global__ void zero_scalar_kernel(float* p) { *p = 0.0f; }

// ---------------- distortion: sort edges by key = qd*B + s ----------------
__global__ void histK_kernel(const int* __restrict__ s_idx, const int* __restrict__ d_idx,
                             int* __restrict__ histK, int E2, int B, int quarter)
{
    int e = blockIdx.x * blockDim.x + threadIdx.x;
    if (e >= E2) return;
    int qd = d_idx[e] / quarter; if (qd > 3) qd = 3;
    atomicAdd(&histK[qd * B + s_idx[e]], 1);
}

__global__ void combineK_kernel(const int* __restrict__ lexclK, const int* __restrict__ partialsK,
                                int* __restrict__ offK, int* __restrict__ curK, int nk, int E2)
{
    int i = blockIdx.x * blockDim.x + threadIdx.x;
    if (i >= nk) return;
    int o = lexclK[i] + partialsK[i >> 10];
    offK[i] = o;
    curK[i] = o;
    if (i == 0) offK[nk] = E2;
}

__global__ void scatterK_kernel(const int* __restrict__ s_idx, const int* __restrict__ d_idx,
                                const float* __restrict__ dis,
                                int* __restrict__ curK, int* __restrict__ dD,
                                float* __restrict__ disD, int E2, int B, int quarter)
{
    int e = blockIdx.x * blockDim.x + threadIdx.x;
    if (e >= E2) return;
    int d = d_idx[e];
    int qd = d / quarter; if (qd > 3) qd = 3;
    int pos = atomicAdd(&curK[qd * B + s_idx[e]], 1);
    dD[pos] = d;
    disD[pos] = dis[e];
}

// Shard = (qd, s-half) pinned to XCD (blockIdx&7); grid = 1024 blocks.
// QUARTER-WAVE (16 lanes) per edge: lane ql holds float4 ql+16k -> its k-th
// float4 is expert k. 4-round butterfly makes all 8 expert diffs lane-local.
__global__ __launch_bounds__(256)
void distortion6_kernel(const float* __restrict__ emb, const float* __restrict__ gate,
                        const int* __restrict__ offK, const int* __restrict__ dD,
                        const float* __restrict__ disD,
                        float* __restrict__ loss, int B, int E2)
{
    const int lane = threadIdx.x & 63;
    const int q    = lane >> 4;          // quarter (which edge of the 4)
    const int ql   = lane & 15;          // lane within quarter
    const int xcd  = blockIdx.x & 7;
    const int bid  = blockIdx.x >> 3;
    const int wv   = threadIdx.x >> 6;   // 0..3
    const int wIdx = bid * 4 + wv;       // wave index within shard
    const int nws  = (gridDim.x >> 3) * 4; // waves per shard

    const int qd   = xcd >> 1;
    const int sh   = xcd & 1;
    const int halfB = B >> 1;
    const int k0 = qd * B + sh * halfB;
    const int k1 = qd * B + (sh ? B : halfB);

    const float4* emb4  = (const float4*)emb;
    const float4* gate4 = (const float4*)gate;

    float lsum = 0.0f;
    for (int k = k0 + wIdx; k < k1; k += nws) {
        const int j0 = offK[k];
        const int j1 = offK[k + 1];
        if (j0 == j1) continue;
        const int s = k - qd * B;

        const float4* es = emb4 + (size_t)s * 128;
        float4 a0 = es[ql];
        float4 a1 = es[ql + 16];
        float4 a2 = es[ql + 32];
        float4 a3 = es[ql + 48];
        float4 a4 = es[ql + 64];
        float4 a5 = es[ql + 80];
        float4 a6 = es[ql + 96];
        float4 a7 = es[ql + 112];
        float4 gs0 = gate4[(size_t)s * 2];
        float4 gs1 = gate4[(size_t)s * 2 + 1];

        for (int j = j0 + q; j < j1; j += 4) {
            int d = dD[j];
            float dv = disD[j];
            const float4* ed = emb4 + (size_t)d * 128;
            float4 b0 = ed[ql];
            float4 b1 = ed[ql + 16];
            float4 b2 = ed[ql + 32];
            float4 b3 = ed[ql + 48];
            float4 b4 = ed[ql + 64];
            float4 b5 = ed[ql + 80];
            float4 b6 = ed[ql + 96];
            float4 b7 = ed[ql + 112];
            float4 gd0 = gate4[(size_t)d * 2];
            float4 gd1 = gate4[(size_t)d * 2 + 1];

            float p[NEXP];
            float dx;
            dx = a0.x - b0.x; p[0]  = dx * dx;
            dx = a0.y - b0.y; p[0] += dx * dx;
            dx = a0.z - b0.z; p[0] += dx * dx;
            dx = a0.w - b0.w; p[0] += dx * dx;
            dx = a1.x - b1.x; p[1]  = dx * dx;
            dx = a1.y - b1.y; p[1] += dx * dx;
            dx = a1.z - b1.z; p[1] += dx * dx;
            dx = a1.w - b1.w; p[1] += dx * dx;
            dx = a2.x - b2.x; p[2]  = dx * dx;
            dx = a2.y - b2.y; p[2] += dx * dx;
            dx = a2.z - b2.z; p[2] += dx * dx;
            dx = a2.w - b2.w; p[2] += dx * dx;
            dx = a3.x - b3.x; p[3]  = dx * dx;
            dx = a3.y - b3.y; p[3] += dx * dx;
            dx = a3.z - b3.z; p[3] += dx * dx;
            dx = a3.w - b3.w; p[3] += dx * dx;
            dx = a4.x - b4.x; p[4]  = dx * dx;
            dx = a4.y - b4.y; p[4] += dx * dx;
            dx = a4.z - b4.z; p[4] += dx * dx;
            dx = a4.w - b4.w; p[4] += dx * dx;
            dx = a5.x - b5.x; p[5]  = dx * dx;
            dx = a5.y - b5.y; p[5] += dx * dx;
            dx = a5.z - b5.z; p[5] += dx * dx;
            dx = a5.w - b5.w; p[5] += dx * dx;
            dx = a6.x - b6.x; p[6]  = dx * dx;
            dx = a6.y - b6.y; p[6] += dx * dx;
            dx = a6.z - b6.z; p[6] += dx * dx;
            dx = a6.w - b6.w; p[6] += dx * dx;
            dx = a7.x - b7.x; p[7]  = dx * dx;
            dx = a7.y - b7.y; p[7] += dx * dx;
            dx = a7.z - b7.z; p[7] += dx * dx;
            dx = a7.w - b7.w; p[7] += dx * dx;

            // butterfly within the 16-lane quarter -> all lanes hold full sums
#pragma unroll
            for (int off = 1; off < 16; off <<= 1) {
#pragma unroll
                for (int t = 0; t < NEXP; ++t) p[t] += __shfl_xor(p[t], off);
            }

            float gp[NEXP] = { gs0.x * gd0.x, gs0.y * gd0.y, gs0.z * gd0.z, gs0.w * gd0.w,
                               gs1.x * gd1.x, gs1.y * gd1.y, gs1.z * gd1.z, gs1.w * gd1.w };
            float m = gp[0];
#pragma unroll
            for (int t = 1; t < NEXP; ++t) m = fmaxf(m, gp[t]);
            float se = 0.0f;
#pragma unroll
            for (int t = 0; t < NEXP; ++t) { gp[t] = expf(gp[t] - m); se += gp[t]; }
            float dsum = 0.0f;
#pragma unroll
            for (int t = 0; t < NEXP; ++t) dsum += p[t] * gp[t];

            lsum += fabsf((dsum / se) / dv - 1.0f);
        }
    }
    // all 16 lanes of a quarter hold the same lsum; xor 16 then 32 sums quarters
    lsum += __shfl_xor(lsum, 16);
    lsum += __shfl_xor(lsum, 32);
    if (lane == 0) atomicAdd(loss, lsum / (float)E2);
}

// ---------------- launch ----------------
extern "C" void kernel_launch(void* const* d_in, const int* in_sizes, int n_in,
                              void* d_out, int out_size, void* d_ws, size_t ws_size,
                              hipStream_t stream)
{
    const float* x0   = (const float*)d_in[0];
    const float* x1   = (const float*)d_in[1];
    const float* W1   = (const float*)d_in[2];
    const float* b1   = (const float*)d_in[3];
    const float* W2   = (const float*)d_in[4];
    const float* b2   = (const float*)d_in[5];
    const float* Wc   = (const float*)d_in[6];
    const float* bc   = (const float*)d_in[7];
    const float* emb  = (const float*)d_in[8];
    const float* dis  = (const float*)d_in[9];
    const int*   ei0  = (const int*)d_in[10];
    const int*   ei1  = (const int*)d_in[11];
    const int*   bat0 = (const int*)d_in[12];
    const int*   bat1 = (const int*)d_in[13];
    const int*   ei2  = (const int*)d_in[14];

    const int N  = in_sizes[0] / IN_F;
    const int E  = in_sizes[10] / 2;
    const int B  = in_sizes[8] / (NEXP * EMB);
    const int E2 = in_sizes[14] / 2;
    const int n2 = 2 * N;
    const int nk = 4 * B;                          // sort keys
    const int quarter = (B + 3) / 4;

    float* gate_out = (float*)d_out;               // B*NEXP
    float* loss_out = gate_out + (size_t)B * NEXP; // 1

    // workspace layout (floats)
    float* ws      = (float*)d_ws;
    float* dinv    = ws;                           // 2N
    float* Ys      = dinv + n2;                    // 2N*32
    float* Zs      = Ys + (size_t)n2 * OUT_F;      // 2N*32
    float* sdsum   = Zs + (size_t)n2 * OUT_F;      // 2N
    float* pooled  = sdsum + n2;                   // 2B*32
    float* cnt     = pooled + (size_t)2 * B * OUT_F; // 2B
    float* W12     = cnt + 2 * B;                  // 64*32
    float* c1      = W12 + IN_F * OUT_F;           // 32
    float* disD    = c1 + OUT_F;                   // E2
    int*   iws     = (int*)(disD + E2);
    int*   counts  = iws;                          // 2N
    int*   offsets = counts + n2;                  // 2N+1
    int*   cursor  = offsets + n2 + 1;             // 2N
    int*   csr_src = cursor + n2;                  // 2E
    int*   lexcl   = csr_src + 2 * E;              // 2N
    int*   partials= lexcl + n2;                   // <=1024
    int*   histK   = partials + 1024;              // 4B
    int*   lexclK  = histK + nk;                   // 4B
    int*   partialsK = lexclK + nk;                // <=1024 (16 used)
    int*   offK    = partialsK + 1024;             // 4B+1
    int*   curK    = offK + nk + 1;                // 4B
    int*   dD      = curK + nk;                    // E2

    const int TB = 256;
    const int zgrid = 512;
    const int NB2 = (n2 + 1023) / 1024;            // scan blocks over 2N
    const int NBK = (nk + 1023) / 1024;            // scan blocks over 4B keys

    // W12 = W1@W2, c1 = b1@W2 (once)
    w12_kernel<<<1, 1024, 0, stream>>>(W1, W2, b1, W12, c1);

    // ---- fused CSR build over both graphs ----
    zero_i32_kernel<<<zgrid, TB, 0, stream>>>(counts, n2);
    hist2_kernel<<<(2 * E + TB - 1) / TB, TB, 0, stream>>>(ei0, ei1, counts, E, N);
    scan1_kernel<<<NB2, 1024, 0, stream>>>(counts, lexcl, partials, n2);
    scan2_kernel<<<1, 1024, 0, stream>>>(partials, NB2);
    scan3_kernel<<<(n2 + TB - 1) / TB, TB, 0, stream>>>(lexcl, partials, counts,
                                                        offsets, cursor, dinv, n2, 2 * E);
    scatter2_shard_kernel<<<1024, TB, 0, stream>>>(ei0, ei1, cursor, csr_src, E, N, n2);

    // ---- distortion edge sort by key (qd, s) ----
    zero_i32_kernel<<<zgrid, TB, 0, stream>>>(histK, nk);
    histK_kernel<<<(E2 + TB - 1) / TB, TB, 0, stream>>>(ei2, ei2 + E2, histK, E2, B, quarter);
    scan1_kernel<<<NBK, 1024, 0, stream>>>(histK, lexclK, partialsK, nk);
    scan2_kernel<<<1, 1024, 0, stream>>>(partialsK, NBK);
    combineK_kernel<<<(nk + TB - 1) / TB, TB, 0, stream>>>(lexclK, partialsK, offK, curK, nk, E2);
    scatterK_kernel<<<(E2 + TB - 1) / TB, TB, 0, stream>>>(ei2, ei2 + E2, dis,
                                                           curK, dD, disD, E2, B, quarter);

    // ---- encoder: Ys = (X@W12)*dinv ; two aggregation passes ----
    gemm_ys2_kernel<<<(n2 + 7) / 8, 256, 0, stream>>>(x0, x1, W12, dinv, Ys, N, n2);
    csr_agg32_kernel<0><<<(n2 + 7) / 8, TB, 0, stream>>>(csr_src, offsets, Ys, dinv,
                                                         sdsum, nullptr, nullptr, Zs, n2);
    csr_agg32_kernel<1><<<(n2 + 7) / 8, TB, 0, stream>>>(csr_src, offsets, Zs, dinv,
                                                         sdsum, c1, b2, Ys, n2);

    // ---- mean pool (both graphs) ----
    zero_f32_kernel<<<zgrid, TB, 0, stream>>>(pooled, (long long)2 * B * OUT_F);
    zero_f32_kernel<<<zgrid, TB, 0, stream>>>(cnt, 2 * B);
    pool_sum2_kernel<<<((n2 * 32) + TB - 1) / TB, TB, 0, stream>>>(Ys, bat0, bat1,
                                                                   pooled, cnt, N, n2, B);
    pool_div_kernel<<<((2 * B * OUT_F) + TB - 1) / TB, TB, 0, stream>>>(pooled, cnt, 2 * B);

    // ---- gate ----
    gate_kernel<<<(B + TB - 1) / TB, TB, 0, stream>>>(pooled, pooled + (size_t)B * OUT_F,
                                                      Wc, bc, gate_out, B);

    // ---- distortion loss (XCD-sharded, quarter-wave per edge, 1024 blocks) ----
    zero_scalar_kernel<<<1, 1, 0, stream>>>(loss_out);
    distortion6_kernel<<<1024, TB, 0, stream>>>(emb, gate_out, offK, dD, disD,
                                                loss_out, B, E2);
}

// Round 24
// 397.674 us; speedup vs baseline: 3.9109x; 1.0260x over previous
//
#include <hip/hip_runtime.h>
#include <math.h>

// ---------------- constants from the reference ----------------
constexpr int IN_F  = 64;
constexpr int HID_F = 64;
constexpr int OUT_F = 32;
constexpr int NEXP  = 8;
constexpr int EMB   = 64;   // emb_dim

// Encoder is linear: h2 = A^(A^(X W12)) + t*(b1 W2) + b2, W12 = W1@W2.
// r23: Ys and Zs stored as bf16 -> the agg gather reads one 64B line
// per edge-row instead of two 128B lines (dominant remaining traffic).
// Final P stays f32. Error budget ~1e-3 on gate vs ~0.015 threshold.
// Distortion: (d-quarter,s)-sorted, XCD-pinned, quarter-wave/edge, 1024 blocks.
// Scatter: dst-range-sharded x8 (r19 optimum; nt and two-phase both failed).

__device__ __forceinline__ unsigned short f2b(float x) {
    unsigned u = __float_as_uint(x);
    unsigned r = (u + 0x7FFFu + ((u >> 16) & 1u)) >> 16;   // round-nearest-even
    return (unsigned short)r;
}
__device__ __forceinline__ float b2f(unsigned short h) {
    return __uint_as_float(((unsigned)h) << 16);
}

// ---------------- utility kernels ----------------
__global__ void zero_f32_kernel(float* __restrict__ p, long long n) {
    long long i = (long long)blockIdx.x * blockDim.x + threadIdx.x;
    long long stride = (long long)gridDim.x * blockDim.x;
    for (; i < n; i += stride) p[i] = 0.0f;
}

__global__ void zero_i32_kernel(int* __restrict__ p, long long n) {
    long long i = (long long)blockIdx.x * blockDim.x + threadIdx.x;
    long long stride = (long long)gridDim.x * blockDim.x;
    for (; i < n; i += stride) p[i] = 0;
}

// ---------------- W12 = W1@W2, c1 = b1@W2 (once) ----------------
__global__ __launch_bounds__(1024)
void w12_kernel(const float* __restrict__ W1, const float* __restrict__ W2,
                const float* __restrict__ b1,
                float* __restrict__ W12, float* __restrict__ c1)
{
    __shared__ float sW2[HID_F * OUT_F];
    const int tid = threadIdx.x;
    for (int i = tid; i < HID_F * OUT_F; i += 1024) sW2[i] = W2[i];
    __syncthreads();
    for (int idx = tid; idx < IN_F * OUT_F; idx += 1024) {
        int i = idx >> 5, j = idx & 31;
        float acc = 0.0f;
#pragma unroll
        for (int k = 0; k < HID_F; ++k) acc += W1[i * HID_F + k] * sW2[k * OUT_F + j];
        W12[idx] = acc;
    }
    if (tid < OUT_F) {
        float acc = 0.0f;
#pragma unroll
        for (int k = 0; k < HID_F; ++k) acc += b1[k] * sW2[k * OUT_F + tid];
        c1[tid] = acc;
    }
}

// ---------------- fused CSR build over both graphs ----------------
__global__ void hist2_kernel(const int* __restrict__ ei0, const int* __restrict__ ei1,
                             int* __restrict__ counts, int E, int N)
{
    int e = blockIdx.x * blockDim.x + threadIdx.x;
    if (e >= 2 * E) return;
    int d = (e < E) ? ei0[E + e] : (ei1[E + (e - E)] + N);
    atomicAdd(&counts[d], 1);
}

// two-level exclusive scan (race-free)
__global__ __launch_bounds__(1024)
void scan1_kernel(const int* __restrict__ counts, int* __restrict__ lexcl,
                  int* __restrict__ partials, int N)
{
    __shared__ int wsum[16];
    const int tid  = threadIdx.x;
    const int lane = tid & 63;
    const int wv   = tid >> 6;
    const int i    = blockIdx.x * 1024 + tid;

    int v = (i < N) ? counts[i] : 0;
    int x = v;
#pragma unroll
    for (int off = 1; off < 64; off <<= 1) {
        int t = __shfl_up(x, off);
        if (lane >= off) x += t;
    }
    if (lane == 63) wsum[wv] = x;
    __syncthreads();
    int woff = 0;
    for (int w = 0; w < wv; ++w) woff += wsum[w];
    if (i < N) lexcl[i] = woff + x - v;
    if (tid == 1023) partials[blockIdx.x] = woff + x;
}

__global__ __launch_bounds__(1024)
void scan2_kernel(int* __restrict__ partials, int NB)
{
    __shared__ int wsum[16];
    const int tid  = threadIdx.x;
    const int lane = tid & 63;
    const int wv   = tid >> 6;
    int v = (tid < NB) ? partials[tid] : 0;
    int x = v;
#pragma unroll
    for (int off = 1; off < 64; off <<= 1) {
        int t = __shfl_up(x, off);
        if (lane >= off) x += t;
    }
    if (lane == 63) wsum[wv] = x;
    __syncthreads();
    int woff = 0;
    for (int w = 0; w < wv; ++w) woff += wsum[w];
    if (tid < NB) partials[tid] = woff + x - v;
}

// combine -> offsets/cursor, dinv = rsqrt(deg+1)
__global__ void scan3_kernel(const int* __restrict__ lexcl, const int* __restrict__ partials,
                             const int* __restrict__ counts,
                             int* __restrict__ offsets, int* __restrict__ cursor,
                             float* __restrict__ dinv, int n2, int e2tot)
{
    int i = blockIdx.x * blockDim.x + threadIdx.x;
    if (i >= n2) return;
    int o = lexcl[i] + partials[i >> 10];
    offsets[i] = o;
    cursor[i]  = o;
    dinv[i] = rsqrtf((float)counts[i] + 1.0f);
    if (i == 0) offsets[n2] = e2tot;
}

// dst-range-sharded scatter (r15-verified; r19 best at 73.6us)
__global__ __launch_bounds__(256)
void scatter2_shard_kernel(const int* __restrict__ ei0, const int* __restrict__ ei1,
                           int* __restrict__ cursor, int* __restrict__ csr_src,
                           int E, int N, int n2)
{
    const int shard   = blockIdx.x & 7;
    const int bid     = blockIdx.x >> 3;
    const int nblocks = gridDim.x >> 3;
    const int lo = (int)(((long long)n2 * shard) >> 3);
    const int hi = (int)(((long long)n2 * (shard + 1)) >> 3);

    long long start  = (long long)bid * blockDim.x + threadIdx.x;
    long long stride = (long long)nblocks * blockDim.x;
    const long long e2 = 2LL * E;
    for (long long e = start; e < e2; e += stride) {
        int s, d;
        if (e < E) { s = ei0[e];                 d = ei0[E + e]; }
        else       { s = ei1[e - E] + N;         d = ei1[E + (e - E)] + N; }
        if (d >= lo && d < hi) {
            int pos = atomicAdd(&cursor[d], 1);
            csr_src[pos] = s;
        }
    }
}

// ---------------- GEMM: Ys(bf16) = (X @ W12) * dinv over 2N rows ----------------
__global__ __launch_bounds__(256)
void gemm_ys2_kernel(const float* __restrict__ x0, const float* __restrict__ x1,
                     const float* __restrict__ W12, const float* __restrict__ dinv,
                     unsigned short* __restrict__ Ysh, int N, int n2)
{
    __shared__ float Ws[IN_F * OUT_F];
    __shared__ float xs[8 * IN_F];
    const int tid = threadIdx.x;

    for (int i = tid; i < IN_F * OUT_F; i += 256) Ws[i] = W12[i];
    const int row0 = blockIdx.x * 8;
    for (int i = tid; i < 8 * IN_F; i += 256) {
        int r = i >> 6;
        int rr = row0 + r;
        float v = 0.0f;
        if (rr < n2) {
            v = (rr < N) ? x0[(size_t)rr * IN_F + (i & 63)]
                         : x1[(size_t)(rr - N) * IN_F + (i & 63)];
        }
        xs[i] = v;
    }
    __syncthreads();

    const int r = tid >> 5;
    const int c = tid & 31;
    const int row = row0 + r;
    if (row >= n2) return;

    float acc = 0.0f;
#pragma unroll
    for (int k = 0; k < IN_F; ++k) acc += xs[r * IN_F + k] * Ws[k * OUT_F + c];

    Ysh[(size_t)row * OUT_F + c] = f2b(acc * dinv[row]);
}

// ---------------- CSR gather-aggregate, 32-wide, unroll 8, bf16 operand ----
// MODE 0: outh = bf16(dinv^2 * (self + sum)); sdsum_i = sum_j dinv_j (coalesced)
// MODE 1: outf = dinv * (self + sum) + t*c1 + b2  (f32), t = dinv*(dinv+sdsum)
template<int MODE>
__global__ __launch_bounds__(256)
void csr_agg32_kernel(const int* __restrict__ csr_src, const int* __restrict__ offsets,
                      const unsigned short* __restrict__ in, const float* __restrict__ dinv,
                      float* __restrict__ sdsum, const float* __restrict__ c1,
                      const float* __restrict__ b2,
                      unsigned short* __restrict__ outh, float* __restrict__ outf, int n)
{
    constexpr int F = OUT_F;              // 32
    const int lane = threadIdx.x & 63;
    const int wid  = (blockIdx.x * (blockDim.x >> 6)) + (threadIdx.x >> 6);
    const int sub  = lane >> 5;           // 2 nodes per wave
    const int f    = lane & 31;
    const int node = wid * 2 + sub;
    const int lbase = sub * F;

    const bool valid = (node < n);
    const int nc   = valid ? node : 0;
    const int off0 = offsets[nc];
    const int off1 = valid ? offsets[nc + 1] : off0;

    float acc0 = valid ? b2f(in[(size_t)nc * F + f]) : 0.0f;   // self term
    float acc1 = 0.0f, acc2 = 0.0f, acc3 = 0.0f;
    float dsum = 0.0f;                                    // MODE 0 only
    for (int k = off0; k < off1; k += F) {
        int nk = off1 - k; if (nk > F) nk = F;
        int sj = (f < nk) ? csr_src[k + f] : 0;
        if (MODE == 0) {
            float dv = dinv[sj];
            dsum += (f < nk) ? dv : 0.0f;
        }
        int t = 0;
        for (; t + 8 <= nk; t += 8) {
            int s0 = __shfl(sj, lbase + t);
            int s1 = __shfl(sj, lbase + t + 1);
            int s2 = __shfl(sj, lbase + t + 2);
            int s3 = __shfl(sj, lbase + t + 3);
            int s4 = __shfl(sj, lbase + t + 4);
            int s5 = __shfl(sj, lbase + t + 5);
            int s6 = __shfl(sj, lbase + t + 6);
            int s7 = __shfl(sj, lbase + t + 7);
            float v0 = b2f(in[(size_t)s0 * F + f]);
            float v1 = b2f(in[(size_t)s1 * F + f]);
            float v2 = b2f(in[(size_t)s2 * F + f]);
            float v3 = b2f(in[(size_t)s3 * F + f]);
            float v4 = b2f(in[(size_t)s4 * F + f]);
            float v5 = b2f(in[(size_t)s5 * F + f]);
            float v6 = b2f(in[(size_t)s6 * F + f]);
            float v7 = b2f(in[(size_t)s7 * F + f]);
            acc0 += v0 + v4;
            acc1 += v1 + v5;
            acc2 += v2 + v6;
            acc3 += v3 + v7;
        }
        for (; t < nk; ++t) {
            int s = __shfl(sj, lbase + t);
            acc0 += b2f(in[(size_t)s * F + f]);
        }
    }
    if (MODE == 0) {
#pragma unroll
        for (int off = 1; off < 32; off <<= 1) dsum += __shfl_xor(dsum, off);
    }
    if (valid) {
        float di = dinv[node];
        float s = (acc0 + acc1) + (acc2 + acc3);
        if (MODE == 0) {
            outh[(size_t)node * F + f] = f2b(di * di * s);
            if (f == 0) sdsum[node] = dsum;
        } else {
            float t = di * (di + sdsum[node]);
            outf[(size_t)node * F + f] = di * s + t * c1[f] + b2[f];
        }
    }
}

// ---------------- mean pool over both graphs (2N nodes -> 2B graphs) ----------------
__global__ void pool_sum2_kernel(const float* __restrict__ h,
                                 const int* __restrict__ bat0, const int* __restrict__ bat1,
                                 float* __restrict__ pooled, float* __restrict__ cnt,
                                 int N, int n2, int B)
{
    int t = blockIdx.x * blockDim.x + threadIdx.x;
    int i = t >> 5;          // node
    int f = t & 31;          // feature
    if (i >= n2) return;
    int g = (i < N) ? bat0[i] : (bat1[i - N] + B);
    atomicAdd(&pooled[(size_t)g * OUT_F + f], h[(size_t)i * OUT_F + f]);
    if (f == 0) atomicAdd(&cnt[g], 1.0f);
}

__global__ void pool_div_kernel(float* __restrict__ pooled, const float* __restrict__ cnt, int B2)
{
    int t = blockIdx.x * blockDim.x + threadIdx.x;
    if (t >= B2 * OUT_F) return;
    int g = t >> 5;
    pooled[t] /= fmaxf(cnt[g], 1.0f);
}

// ---------------- gate: softmax([p0|p1] @ Wc + bc) ----------------
__global__ void gate_kernel(const float* __restrict__ p0, const float* __restrict__ p1,
                            const float* __restrict__ Wc, const float* __restrict__ bc,
                            float* __restrict__ gate, int B)
{
    int g = blockIdx.x * blockDim.x + threadIdx.x;
    if (g >= B) return;
    float xv[2 * OUT_F];
#pragma unroll
    for (int k = 0; k < OUT_F; ++k) xv[k] = p0[(size_t)g * OUT_F + k];
#pragma unroll
    for (int k = 0; k < OUT_F; ++k) xv[OUT_F + k] = p1[(size_t)g * OUT_F + k];

    float lg[NEXP];
    float m = -1e30f;
#pragma unroll
    for (int e = 0; e < NEXP; ++e) {
        float acc = bc[e];
#pragma unroll
        for (int k = 0; k < 2 * OUT_F; ++k) acc += xv[k] * Wc[k * NEXP + e];
        lg[e] = acc;
        m = fmaxf(m, acc);
    }
    float se = 0.0f;
#pragma unroll
    for (int e = 0; e < NEXP; ++e) { lg[e] = expf(lg[e] - m); se += lg[e]; }
    float inv = 1.0f / se;
#pragma unroll
    for (int e = 0; e < NEXP; ++e) gate[(size_t)g * NEXP + e] = lg[e] * inv;
}

__global__ void zero_scalar_kernel(float* p) { *p = 0.0f; }

// ---------------- distortion: sort edges by key = qd*B + s ----------------
__global__ void histK_kernel(const int* __restrict__ s_idx, const int* __restrict__ d_idx,
                             int* __restrict__ histK, int E2, int B, int quarter)
{
    int e = blockIdx.x * blockDim.x + threadIdx.x;
    if (e >= E2) return;
    int qd = d_idx[e] / quarter; if (qd > 3) qd = 3;
    atomicAdd(&histK[qd * B + s_idx[e]], 1);
}

__global__ void combineK_kernel(const int* __restrict__ lexclK, const int* __restrict__ partialsK,
                                int* __restrict__ offK, int* __restrict__ curK, int nk, int E2)
{
    int i = blockIdx.x * blockDim.x + threadIdx.x;
    if (i >= nk) return;
    int o = lexclK[i] + partialsK[i >> 10];
    offK[i] = o;
    curK[i] = o;
    if (i == 0) offK[nk] = E2;
}

__global__ void scatterK_kernel(const int* __restrict__ s_idx, const int* __restrict__ d_idx,
                                const float* __restrict__ dis,
                                int* __restrict__ curK, int* __restrict__ dD,
                                float* __restrict__ disD, int E2, int B, int quarter)
{
    int e = blockIdx.x * blockDim.x + threadIdx.x;
    if (e >= E2) return;
    int d = d_idx[e];
    int qd = d / quarter; if (qd > 3) qd = 3;
    int pos = atomicAdd(&curK[qd * B + s_idx[e]], 1);
    dD[pos] = d;
    disD[pos] = dis[e];
}

// Shard = (qd, s-half) pinned to XCD (blockIdx&7); grid = 1024 blocks.
// QUARTER-WAVE (16 lanes) per edge: lane ql holds float4 ql+16k -> its k-th
// float4 is expert k. 4-round butterfly makes all 8 expert diffs lane-local.
__global__ __launch_bounds__(256)
void distortion6_kernel(const float* __restrict__ emb, const float* __restrict__ gate,
                        const int* __restrict__ offK, const int* __restrict__ dD,
                        const float* __restrict__ disD,
                        float* __restrict__ loss, int B, int E2)
{
    const int lane = threadIdx.x & 63;
    const int q    = lane >> 4;          // quarter (which edge of the 4)
    const int ql   = lane & 15;          // lane within quarter
    const int xcd  = blockIdx.x & 7;
    const int bid  = blockIdx.x >> 3;
    const int wv   = threadIdx.x >> 6;   // 0..3
    const int wIdx = bid * 4 + wv;       // wave index within shard
    const int nws  = (gridDim.x >> 3) * 4; // waves per shard

    const int qd   = xcd >> 1;
    const int sh   = xcd & 1;
    const int halfB = B >> 1;
    const int k0 = qd * B + sh * halfB;
    const int k1 = qd * B + (sh ? B : halfB);

    const float4* emb4  = (const float4*)emb;
    const float4* gate4 = (const float4*)gate;

    float lsum = 0.0f;
    for (int k = k0 + wIdx; k < k1; k += nws) {
        const int j0 = offK[k];
        const int j1 = offK[k + 1];
        if (j0 == j1) continue;
        const int s = k - qd * B;

        const float4* es = emb4 + (size_t)s * 128;
        float4 a0 = es[ql];
        float4 a1 = es[ql + 16];
        float4 a2 = es[ql + 32];
        float4 a3 = es[ql + 48];
        float4 a4 = es[ql + 64];
        float4 a5 = es[ql + 80];
        float4 a6 = es[ql + 96];
        float4 a7 = es[ql + 112];
        float4 gs0 = gate4[(size_t)s * 2];
        float4 gs1 = gate4[(size_t)s * 2 + 1];

        for (int j = j0 + q; j < j1; j += 4) {
            int d = dD[j];
            float dv = disD[j];
            const float4* ed = emb4 + (size_t)d * 128;
            float4 b0 = ed[ql];
            float4 b1 = ed[ql + 16];
            float4 b2 = ed[ql + 32];
            float4 b3 = ed[ql + 48];
            float4 b4 = ed[ql + 64];
            float4 b5 = ed[ql + 80];
            float4 b6 = ed[ql + 96];
            float4 b7 = ed[ql + 112];
            float4 gd0 = gate4[(size_t)d * 2];
            float4 gd1 = gate4[(size_t)d * 2 + 1];

            float p[NEXP];
            float dx;
            dx = a0.x - b0.x; p[0]  = dx * dx;
            dx = a0.y - b0.y; p[0] += dx * dx;
            dx = a0.z - b0.z; p[0] += dx * dx;
            dx = a0.w - b0.w; p[0] += dx * dx;
            dx = a1.x - b1.x; p[1]  = dx * dx;
            dx = a1.y - b1.y; p[1] += dx * dx;
            dx = a1.z - b1.z; p[1] += dx * dx;
            dx = a1.w - b1.w; p[1] += dx * dx;
            dx = a2.x - b2.x; p[2]  = dx * dx;
            dx = a2.y - b2.y; p[2] += dx * dx;
            dx = a2.z - b2.z; p[2] += dx * dx;
            dx = a2.w - b2.w; p[2] += dx * dx;
            dx = a3.x - b3.x; p[3]  = dx * dx;
            dx = a3.y - b3.y; p[3] += dx * dx;
            dx = a3.z - b3.z; p[3] += dx * dx;
            dx = a3.w - b3.w; p[3] += dx * dx;
            dx = a4.x - b4.x; p[4]  = dx * dx;
            dx = a4.y - b4.y; p[4] += dx * dx;
            dx = a4.z - b4.z; p[4] += dx * dx;
            dx = a4.w - b4.w; p[4] += dx * dx;
            dx = a5.x - b5.x; p[5]  = dx * dx;
            dx = a5.y - b5.y; p[5] += dx * dx;
            dx = a5.z - b5.z; p[5] += dx * dx;
            dx = a5.w - b5.w; p[5] += dx * dx;
            dx = a6.x - b6.x; p[6]  = dx * dx;
            dx = a6.y - b6.y; p[6] += dx * dx;
            dx = a6.z - b6.z; p[6] += dx * dx;
            dx = a6.w - b6.w; p[6] += dx * dx;
            dx = a7.x - b7.x; p[7]  = dx * dx;
            dx = a7.y - b7.y; p[7] += dx * dx;
            dx = a7.z - b7.z; p[7] += dx * dx;
            dx = a7.w - b7.w; p[7] += dx * dx;

            // butterfly within the 16-lane quarter -> all lanes hold full sums
#pragma unroll
            for (int off = 1; off < 16; off <<= 1) {
#pragma unroll
                for (int t = 0; t < NEXP; ++t) p[t] += __shfl_xor(p[t], off);
            }

            float gp[NEXP] = { gs0.x * gd0.x, gs0.y * gd0.y, gs0.z * gd0.z, gs0.w * gd0.w,
                               gs1.x * gd1.x, gs1.y * gd1.y, gs1.z * gd1.z, gs1.w * gd1.w };
            float m = gp[0];
#pragma unroll
            for (int t = 1; t < NEXP; ++t) m = fmaxf(m, gp[t]);
            float se = 0.0f;
#pragma unroll
            for (int t = 0; t < NEXP; ++t) { gp[t] = expf(gp[t] - m); se += gp[t]; }
            float dsum = 0.0f;
#pragma unroll
            for (int t = 0; t < NEXP; ++t) dsum += p[t] * gp[t];

            lsum += fabsf((dsum / se) / dv - 1.0f);
        }
    }
    // all 16 lanes of a quarter hold the same lsum; xor 16 then 32 sums quarters
    lsum += __shfl_xor(lsum, 16);
    lsum += __shfl_xor(lsum, 32);
    if (lane == 0) atomicAdd(loss, lsum / (float)E2);
}

// ---------------- launch ----------------
extern "C" void kernel_launch(void* const* d_in, const int* in_sizes, int n_in,
                              void* d_out, int out_size, void* d_ws, size_t ws_size,
                              hipStream_t stream)
{
    const float* x0   = (const float*)d_in[0];
    const float* x1   = (const float*)d_in[1];
    const float* W1   = (const float*)d_in[2];
    const float* b1   = (const float*)d_in[3];
    const float* W2   = (const float*)d_in[4];
    const float* b2   = (const float*)d_in[5];
    const float* Wc   = (const float*)d_in[6];
    const float* bc   = (const float*)d_in[7];
    const float* emb  = (const float*)d_in[8];
    const float* dis  = (const float*)d_in[9];
    const int*   ei0  = (const int*)d_in[10];
    const int*   ei1  = (const int*)d_in[11];
    const int*   bat0 = (const int*)d_in[12];
    const int*   bat1 = (const int*)d_in[13];
    const int*   ei2  = (const int*)d_in[14];

    const int N  = in_sizes[0] / IN_F;
    const int E  = in_sizes[10] / 2;
    const int B  = in_sizes[8] / (NEXP * EMB);
    const int E2 = in_sizes[14] / 2;
    const int n2 = 2 * N;
    const int nk = 4 * B;                          // sort keys
    const int quarter = (B + 3) / 4;

    float* gate_out = (float*)d_out;               // B*NEXP
    float* loss_out = gate_out + (size_t)B * NEXP; // 1

    // workspace layout (floats)
    float* ws      = (float*)d_ws;
    float* dinv    = ws;                           // 2N
    float* Ys      = dinv + n2;                    // 2N*32 f32 region (P final; bf16 Ysh aliases)
    float* Zs      = Ys + (size_t)n2 * OUT_F;      // 2N*32 f32 region (bf16 Zsh aliases)
    float* sdsum   = Zs + (size_t)n2 * OUT_F;      // 2N
    float* pooled  = sdsum + n2;                   // 2B*32
    float* cnt     = pooled + (size_t)2 * B * OUT_F; // 2B
    float* W12     = cnt + 2 * B;                  // 64*32
    float* c1      = W12 + IN_F * OUT_F;           // 32
    float* disD    = c1 + OUT_F;                   // E2
    int*   iws     = (int*)(disD + E2);
    int*   counts  = iws;                          // 2N
    int*   offsets = counts + n2;                  // 2N+1
    int*   cursor  = offsets + n2 + 1;             // 2N
    int*   csr_src = cursor + n2;                  // 2E
    int*   lexcl   = csr_src + 2 * E;              // 2N
    int*   partials= lexcl + n2;                   // <=1024
    int*   histK   = partials + 1024;              // 4B
    int*   lexclK  = histK + nk;                   // 4B
    int*   partialsK = lexclK + nk;                // <=1024 (16 used)
    int*   offK    = partialsK + 1024;             // 4B+1
    int*   curK    = offK + nk + 1;                // 4B
    int*   dD      = curK + nk;                    // E2

    unsigned short* Ysh = (unsigned short*)Ys;     // bf16 Ys (first half of region)
    unsigned short* Zsh = (unsigned short*)Zs;     // bf16 Zs
    float* P = Ys;                                 // final f32 h2 (Ysh dead by then)

    const int TB = 256;
    const int zgrid = 512;
    const int NB2 = (n2 + 1023) / 1024;            // scan blocks over 2N
    const int NBK = (nk + 1023) / 1024;            // scan blocks over 4B keys

    // W12 = W1@W2, c1 = b1@W2 (once)
    w12_kernel<<<1, 1024, 0, stream>>>(W1, W2, b1, W12, c1);

    // ---- fused CSR build over both graphs ----
    zero_i32_kernel<<<zgrid, TB, 0, stream>>>(counts, n2);
    hist2_kernel<<<(2 * E + TB - 1) / TB, TB, 0, stream>>>(ei0, ei1, counts, E, N);
    scan1_kernel<<<NB2, 1024, 0, stream>>>(counts, lexcl, partials, n2);
    scan2_kernel<<<1, 1024, 0, stream>>>(partials, NB2);
    scan3_kernel<<<(n2 + TB - 1) / TB, TB, 0, stream>>>(lexcl, partials, counts,
                                                        offsets, cursor, dinv, n2, 2 * E);
    scatter2_shard_kernel<<<1024, TB, 0, stream>>>(ei0, ei1, cursor, csr_src, E, N, n2);

    // ---- distortion edge sort by key (qd, s) ----
    zero_i32_kernel<<<zgrid, TB, 0, stream>>>(histK, nk);
    histK_kernel<<<(E2 + TB - 1) / TB, TB, 0, stream>>>(ei2, ei2 + E2, histK, E2, B, quarter);
    scan1_kernel<<<NBK, 1024, 0, stream>>>(histK, lexclK, partialsK, nk);
    scan2_kernel<<<1, 1024, 0, stream>>>(partialsK, NBK);
    combineK_kernel<<<(nk + TB - 1) / TB, TB, 0, stream>>>(lexclK, partialsK, offK, curK, nk, E2);
    scatterK_kernel<<<(E2 + TB - 1) / TB, TB, 0, stream>>>(ei2, ei2 + E2, dis,
                                                           curK, dD, disD, E2, B, quarter);

    // ---- encoder: Ys(bf16) = (X@W12)*dinv ; two bf16-operand agg passes ----
    gemm_ys2_kernel<<<(n2 + 7) / 8, 256, 0, stream>>>(x0, x1, W12, dinv, Ysh, N, n2);
    csr_agg32_kernel<0><<<(n2 + 7) / 8, TB, 0, stream>>>(csr_src, offsets, Ysh, dinv,
                                                         sdsum, nullptr, nullptr,
                                                         Zsh, nullptr, n2);
    csr_agg32_kernel<1><<<(n2 + 7) / 8, TB, 0, stream>>>(csr_src, offsets, Zsh, dinv,
                                                         sdsum, c1, b2,
                                                         nullptr, P, n2);

    // ---- mean pool (both graphs) ----
    zero_f32_kernel<<<zgrid, TB, 0, stream>>>(pooled, (long long)2 * B * OUT_F);
    zero_f32_kernel<<<zgrid, TB, 0, stream>>>(cnt, 2 * B);
    pool_sum2_kernel<<<((n2 * 32) + TB - 1) / TB, TB, 0, stream>>>(P, bat0, bat1,
                                                                   pooled, cnt, N, n2, B);
    pool_div_kernel<<<((2 * B * OUT_F) + TB - 1) / TB, TB, 0, stream>>>(pooled, cnt, 2 * B);

    // ---- gate ----
    gate_kernel<<<(B + TB - 1) / TB, TB, 0, stream>>>(pooled, pooled + (size_t)B * OUT_F,
                                                      Wc, bc, gate_out, B);

    // ---- distortion loss (XCD-sharded, quarter-wave per edge, 1024 blocks) ----
    zero_scalar_kernel<<<1, 1, 0, stream>>>(loss_out);
    distortion6_kernel<<<1024, TB, 0, stream>>>(emb, gate_out, offK, dD, disD,
                                                loss_out, B, E2);
}

// Round 25
// 391.325 us; speedup vs baseline: 3.9744x; 1.0162x over previous
//
#include <hip/hip_runtime.h>
#include <math.h>

// ---------------- constants from the reference ----------------
constexpr int IN_F  = 64;
constexpr int HID_F = 64;
constexpr int OUT_F = 32;
constexpr int NEXP  = 8;
constexpr int EMB   = 64;   // emb_dim

// Encoder is linear: h2 = A^(A^(X W12)) + t*(b1 W2) + b2, W12 = W1@W2.
// Ys/Zs bf16 (r24: 408->398, absmax 1e-3). Distortion (d-quarter,s)-sorted,
// XCD-pinned, quarter-wave/edge, 1024 blocks. Scatter dst-range-sharded x8.
// r25: launch consolidation (23 -> 19 dispatches): fused zeroing (adjacent
// layouts), pool_div + loss-zero folded into gate_kernel. Hot kernels identical.

__device__ __forceinline__ unsigned short f2b(float x) {
    unsigned u = __float_as_uint(x);
    unsigned r = (u + 0x7FFFu + ((u >> 16) & 1u)) >> 16;   // round-nearest-even
    return (unsigned short)r;
}
__device__ __forceinline__ float b2f(unsigned short h) {
    return __uint_as_float(((unsigned)h) << 16);
}

// ---------------- utility kernels ----------------
__global__ void zero_f32_kernel(float* __restrict__ p, long long n) {
    long long i = (long long)blockIdx.x * blockDim.x + threadIdx.x;
    long long stride = (long long)gridDim.x * blockDim.x;
    for (; i < n; i += stride) p[i] = 0.0f;
}

__global__ void zero_i32_kernel(int* __restrict__ p, long long n) {
    long long i = (long long)blockIdx.x * blockDim.x + threadIdx.x;
    long long stride = (long long)gridDim.x * blockDim.x;
    for (; i < n; i += stride) p[i] = 0;
}

// ---------------- W12 = W1@W2, c1 = b1@W2 (once) ----------------
__global__ __launch_bounds__(1024)
void w12_kernel(const float* __restrict__ W1, const float* __restrict__ W2,
                const float* __restrict__ b1,
                float* __restrict__ W12, float* __restrict__ c1)
{
    __shared__ float sW2[HID_F * OUT_F];
    const int tid = threadIdx.x;
    for (int i = tid; i < HID_F * OUT_F; i += 1024) sW2[i] = W2[i];
    __syncthreads();
    for (int idx = tid; idx < IN_F * OUT_F; idx += 1024) {
        int i = idx >> 5, j = idx & 31;
        float acc = 0.0f;
#pragma unroll
        for (int k = 0; k < HID_F; ++k) acc += W1[i * HID_F + k] * sW2[k * OUT_F + j];
        W12[idx] = acc;
    }
    if (tid < OUT_F) {
        float acc = 0.0f;
#pragma unroll
        for (int k = 0; k < HID_F; ++k) acc += b1[k] * sW2[k * OUT_F + tid];
        c1[tid] = acc;
    }
}

// ---------------- fused CSR build over both graphs ----------------
__global__ void hist2_kernel(const int* __restrict__ ei0, const int* __restrict__ ei1,
                             int* __restrict__ counts, int E, int N)
{
    int e = blockIdx.x * blockDim.x + threadIdx.x;
    if (e >= 2 * E) return;
    int d = (e < E) ? ei0[E + e] : (ei1[E + (e - E)] + N);
    atomicAdd(&counts[d], 1);
}

// two-level exclusive scan (race-free)
__global__ __launch_bounds__(1024)
void scan1_kernel(const int* __restrict__ counts, int* __restrict__ lexcl,
                  int* __restrict__ partials, int N)
{
    __shared__ int wsum[16];
    const int tid  = threadIdx.x;
    const int lane = tid & 63;
    const int wv   = tid >> 6;
    const int i    = blockIdx.x * 1024 + tid;

    int v = (i < N) ? counts[i] : 0;
    int x = v;
#pragma unroll
    for (int off = 1; off < 64; off <<= 1) {
        int t = __shfl_up(x, off);
        if (lane >= off) x += t;
    }
    if (lane == 63) wsum[wv] = x;
    __syncthreads();
    int woff = 0;
    for (int w = 0; w < wv; ++w) woff += wsum[w];
    if (i < N) lexcl[i] = woff + x - v;
    if (tid == 1023) partials[blockIdx.x] = woff + x;
}

__global__ __launch_bounds__(1024)
void scan2_kernel(int* __restrict__ partials, int NB)
{
    __shared__ int wsum[16];
    const int tid  = threadIdx.x;
    const int lane = tid & 63;
    const int wv   = tid >> 6;
    int v = (tid < NB) ? partials[tid] : 0;
    int x = v;
#pragma unroll
    for (int off = 1; off < 64; off <<= 1) {
        int t = __shfl_up(x, off);
        if (lane >= off) x += t;
    }
    if (lane == 63) wsum[wv] = x;
    __syncthreads();
    int woff = 0;
    for (int w = 0; w < wv; ++w) woff += wsum[w];
    if (tid < NB) partials[tid] = woff + x - v;
}

// combine -> offsets/cursor, dinv = rsqrt(deg+1)
__global__ void scan3_kernel(const int* __restrict__ lexcl, const int* __restrict__ partials,
                             const int* __restrict__ counts,
                             int* __restrict__ offsets, int* __restrict__ cursor,
                             float* __restrict__ dinv, int n2, int e2tot)
{
    int i = blockIdx.x * blockDim.x + threadIdx.x;
    if (i >= n2) return;
    int o = lexcl[i] + partials[i >> 10];
    offsets[i] = o;
    cursor[i]  = o;
    dinv[i] = rsqrtf((float)counts[i] + 1.0f);
    if (i == 0) offsets[n2] = e2tot;
}

// dst-range-sharded scatter (r15-verified; r19 best at 73.6us)
__global__ __launch_bounds__(256)
void scatter2_shard_kernel(const int* __restrict__ ei0, const int* __restrict__ ei1,
                           int* __restrict__ cursor, int* __restrict__ csr_src,
                           int E, int N, int n2)
{
    const int shard   = blockIdx.x & 7;
    const int bid     = blockIdx.x >> 3;
    const int nblocks = gridDim.x >> 3;
    const int lo = (int)(((long long)n2 * shard) >> 3);
    const int hi = (int)(((long long)n2 * (shard + 1)) >> 3);

    long long start  = (long long)bid * blockDim.x + threadIdx.x;
    long long stride = (long long)nblocks * blockDim.x;
    const long long e2 = 2LL * E;
    for (long long e = start; e < e2; e += stride) {
        int s, d;
        if (e < E) { s = ei0[e];                 d = ei0[E + e]; }
        else       { s = ei1[e - E] + N;         d = ei1[E + (e - E)] + N; }
        if (d >= lo && d < hi) {
            int pos = atomicAdd(&cursor[d], 1);
            csr_src[pos] = s;
        }
    }
}

// ---------------- GEMM: Ys(bf16) = (X @ W12) * dinv over 2N rows ----------------
__global__ __launch_bounds__(256)
void gemm_ys2_kernel(const float* __restrict__ x0, const float* __restrict__ x1,
                     const float* __restrict__ W12, const float* __restrict__ dinv,
                     unsigned short* __restrict__ Ysh, int N, int n2)
{
    __shared__ float Ws[IN_F * OUT_F];
    __shared__ float xs[8 * IN_F];
    const int tid = threadIdx.x;

    for (int i = tid; i < IN_F * OUT_F; i += 256) Ws[i] = W12[i];
    const int row0 = blockIdx.x * 8;
    for (int i = tid; i < 8 * IN_F; i += 256) {
        int r = i >> 6;
        int rr = row0 + r;
        float v = 0.0f;
        if (rr < n2) {
            v = (rr < N) ? x0[(size_t)rr * IN_F + (i & 63)]
                         : x1[(size_t)(rr - N) * IN_F + (i & 63)];
        }
        xs[i] = v;
    }
    __syncthreads();

    const int r = tid >> 5;
    const int c = tid & 31;
    const int row = row0 + r;
    if (row >= n2) return;

    float acc = 0.0f;
#pragma unroll
    for (int k = 0; k < IN_F; ++k) acc += xs[r * IN_F + k] * Ws[k * OUT_F + c];

    Ysh[(size_t)row * OUT_F + c] = f2b(acc * dinv[row]);
}

// ---------------- CSR gather-aggregate, 32-wide, unroll 8, bf16 operand ----
// MODE 0: outh = bf16(dinv^2 * (self + sum)); sdsum_i = sum_j dinv_j (coalesced)
// MODE 1: outf = dinv * (self + sum) + t*c1 + b2  (f32), t = dinv*(dinv+sdsum)
template<int MODE>
__global__ __launch_bounds__(256)
void csr_agg32_kernel(const int* __restrict__ csr_src, const int* __restrict__ offsets,
                      const unsigned short* __restrict__ in, const float* __restrict__ dinv,
                      float* __restrict__ sdsum, const float* __restrict__ c1,
                      const float* __restrict__ b2,
                      unsigned short* __restrict__ outh, float* __restrict__ outf, int n)
{
    constexpr int F = OUT_F;              // 32
    const int lane = threadIdx.x & 63;
    const int wid  = (blockIdx.x * (blockDim.x >> 6)) + (threadIdx.x >> 6);
    const int sub  = lane >> 5;           // 2 nodes per wave
    const int f    = lane & 31;
    const int node = wid * 2 + sub;
    const int lbase = sub * F;

    const bool valid = (node < n);
    const int nc   = valid ? node : 0;
    const int off0 = offsets[nc];
    const int off1 = valid ? offsets[nc + 1] : off0;

    float acc0 = valid ? b2f(in[(size_t)nc * F + f]) : 0.0f;   // self term
    float acc1 = 0.0f, acc2 = 0.0f, acc3 = 0.0f;
    float dsum = 0.0f;                                    // MODE 0 only
    for (int k = off0; k < off1; k += F) {
        int nk = off1 - k; if (nk > F) nk = F;
        int sj = (f < nk) ? csr_src[k + f] : 0;
        if (MODE == 0) {
            float dv = dinv[sj];
            dsum += (f < nk) ? dv : 0.0f;
        }
        int t = 0;
        for (; t + 8 <= nk; t += 8) {
            int s0 = __shfl(sj, lbase + t);
            int s1 = __shfl(sj, lbase + t + 1);
            int s2 = __shfl(sj, lbase + t + 2);
            int s3 = __shfl(sj, lbase + t + 3);
            int s4 = __shfl(sj, lbase + t + 4);
            int s5 = __shfl(sj, lbase + t + 5);
            int s6 = __shfl(sj, lbase + t + 6);
            int s7 = __shfl(sj, lbase + t + 7);
            float v0 = b2f(in[(size_t)s0 * F + f]);
            float v1 = b2f(in[(size_t)s1 * F + f]);
            float v2 = b2f(in[(size_t)s2 * F + f]);
            float v3 = b2f(in[(size_t)s3 * F + f]);
            float v4 = b2f(in[(size_t)s4 * F + f]);
            float v5 = b2f(in[(size_t)s5 * F + f]);
            float v6 = b2f(in[(size_t)s6 * F + f]);
            float v7 = b2f(in[(size_t)s7 * F + f]);
            acc0 += v0 + v4;
            acc1 += v1 + v5;
            acc2 += v2 + v6;
            acc3 += v3 + v7;
        }
        for (; t < nk; ++t) {
            int s = __shfl(sj, lbase + t);
            acc0 += b2f(in[(size_t)s * F + f]);
        }
    }
    if (MODE == 0) {
#pragma unroll
        for (int off = 1; off < 32; off <<= 1) dsum += __shfl_xor(dsum, off);
    }
    if (valid) {
        float di = dinv[node];
        float s = (acc0 + acc1) + (acc2 + acc3);
        if (MODE == 0) {
            outh[(size_t)node * F + f] = f2b(di * di * s);
            if (f == 0) sdsum[node] = dsum;
        } else {
            float t = di * (di + sdsum[node]);
            outf[(size_t)node * F + f] = di * s + t * c1[f] + b2[f];
        }
    }
}

// ---------------- mean pool over both graphs (2N nodes -> 2B graphs) ----------------
__global__ void pool_sum2_kernel(const float* __restrict__ h,
                                 const int* __restrict__ bat0, const int* __restrict__ bat1,
                                 float* __restrict__ pooled, float* __restrict__ cnt,
                                 int N, int n2, int B)
{
    int t = blockIdx.x * blockDim.x + threadIdx.x;
    int i = t >> 5;          // node
    int f = t & 31;          // feature
    if (i >= n2) return;
    int g = (i < N) ? bat0[i] : (bat1[i - N] + B);
    atomicAdd(&pooled[(size_t)g * OUT_F + f], h[(size_t)i * OUT_F + f]);
    if (f == 0) atomicAdd(&cnt[g], 1.0f);
}

// ---------------- gate: softmax([p0|p1] @ Wc + bc), pool-div fused ----------
// Also zeroes loss_out (runs strictly before the distortion kernel).
__global__ void gate_kernel(const float* __restrict__ pooled, const float* __restrict__ cnt,
                            const float* __restrict__ Wc, const float* __restrict__ bc,
                            float* __restrict__ gate, float* __restrict__ loss_out, int B)
{
    int g = blockIdx.x * blockDim.x + threadIdx.x;
    if (g == 0) *loss_out = 0.0f;
    if (g >= B) return;
    float inv0 = 1.0f / fmaxf(cnt[g], 1.0f);
    float inv1 = 1.0f / fmaxf(cnt[B + g], 1.0f);
    float xv[2 * OUT_F];
#pragma unroll
    for (int k = 0; k < OUT_F; ++k) xv[k] = pooled[(size_t)g * OUT_F + k] * inv0;
#pragma unroll
    for (int k = 0; k < OUT_F; ++k)
        xv[OUT_F + k] = pooled[(size_t)(B + g) * OUT_F + k] * inv1;

    float lg[NEXP];
    float m = -1e30f;
#pragma unroll
    for (int e = 0; e < NEXP; ++e) {
        float acc = bc[e];
#pragma unroll
        for (int k = 0; k < 2 * OUT_F; ++k) acc += xv[k] * Wc[k * NEXP + e];
        lg[e] = acc;
        m = fmaxf(m, acc);
    }
    float se = 0.0f;
#pragma unroll
    for (int e = 0; e < NEXP; ++e) { lg[e] = expf(lg[e] - m); se += lg[e]; }
    float inv = 1.0f / se;
#pragma unroll
    for (int e = 0; e < NEXP; ++e) gate[(size_t)g * NEXP + e] = lg[e] * inv;
}

// ---------------- distortion: sort edges by key = qd*B + s ----------------
__global__ void histK_kernel(const int* __restrict__ s_idx, const int* __restrict__ d_idx,
                             int* __restrict__ histK, int E2, int B, int quarter)
{
    int e = blockIdx.x * blockDim.x + threadIdx.x;
    if (e >= E2) return;
    int qd = d_idx[e] / quarter; if (qd > 3) qd = 3;
    atomicAdd(&histK[qd * B + s_idx[e]], 1);
}

__global__ void combineK_kernel(const int* __restrict__ lexclK, const int* __restrict__ partialsK,
                                int* __restrict__ offK, int* __restrict__ curK, int nk, int E2)
{
    int i = blockIdx.x * blockDim.x + threadIdx.x;
    if (i >= nk) return;
    int o = lexclK[i] + partialsK[i >> 10];
    offK[i] = o;
    curK[i] = o;
    if (i == 0) offK[nk] = E2;
}

__global__ void scatterK_kernel(const int* __restrict__ s_idx, const int* __restrict__ d_idx,
                                const float* __restrict__ dis,
                                int* __restrict__ curK, int* __restrict__ dD,
                                float* __restrict__ disD, int E2, int B, int quarter)
{
    int e = blockIdx.x * blockDim.x + threadIdx.x;
    if (e >= E2) return;
    int d = d_idx[e];
    int qd = d / quarter; if (qd > 3) qd = 3;
    int pos = atomicAdd(&curK[qd * B + s_idx[e]], 1);
    dD[pos] = d;
    disD[pos] = dis[e];
}

// Shard = (qd, s-half) pinned to XCD (blockIdx&7); grid = 1024 blocks.
// QUARTER-WAVE (16 lanes) per edge: lane ql holds float4 ql+16k -> its k-th
// float4 is expert k. 4-round butterfly makes all 8 expert diffs lane-local.
__global__ __launch_bounds__(256)
void distortion6_kernel(const float* __restrict__ emb, const float* __restrict__ gate,
                        const int* __restrict__ offK, const int* __restrict__ dD,
                        const float* __restrict__ disD,
                        float* __restrict__ loss, int B, int E2)
{
    const int lane = threadIdx.x & 63;
    const int q    = lane >> 4;          // quarter (which edge of the 4)
    const int ql   = lane & 15;          // lane within quarter
    const int xcd  = blockIdx.x & 7;
    const int bid  = blockIdx.x >> 3;
    const int wv   = threadIdx.x >> 6;   // 0..3
    const int wIdx = bid * 4 + wv;       // wave index within shard
    const int nws  = (gridDim.x >> 3) * 4; // waves per shard

    const int qd   = xcd >> 1;
    const int sh   = xcd & 1;
    const int halfB = B >> 1;
    const int k0 = qd * B + sh * halfB;
    const int k1 = qd * B + (sh ? B : halfB);

    const float4* emb4  = (const float4*)emb;
    const float4* gate4 = (const float4*)gate;

    float lsum = 0.0f;
    for (int k = k0 + wIdx; k < k1; k += nws) {
        const int j0 = offK[k];
        const int j1 = offK[k + 1];
        if (j0 == j1) continue;
        const int s = k - qd * B;

        const float4* es = emb4 + (size_t)s * 128;
        float4 a0 = es[ql];
        float4 a1 = es[ql + 16];
        float4 a2 = es[ql + 32];
        float4 a3 = es[ql + 48];
        float4 a4 = es[ql + 64];
        float4 a5 = es[ql + 80];
        float4 a6 = es[ql + 96];
        float4 a7 = es[ql + 112];
        float4 gs0 = gate4[(size_t)s * 2];
        float4 gs1 = gate4[(size_t)s * 2 + 1];

        for (int j = j0 + q; j < j1; j += 4) {
            int d = dD[j];
            float dv = disD[j];
            const float4* ed = emb4 + (size_t)d * 128;
            float4 b0 = ed[ql];
            float4 b1 = ed[ql + 16];
            float4 b2 = ed[ql + 32];
            float4 b3 = ed[ql + 48];
            float4 b4 = ed[ql + 64];
            float4 b5 = ed[ql + 80];
            float4 b6 = ed[ql + 96];
            float4 b7 = ed[ql + 112];
            float4 gd0 = gate4[(size_t)d * 2];
            float4 gd1 = gate4[(size_t)d * 2 + 1];

            float p[NEXP];
            float dx;
            dx = a0.x - b0.x; p[0]  = dx * dx;
            dx = a0.y - b0.y; p[0] += dx * dx;
            dx = a0.z - b0.z; p[0] += dx * dx;
            dx = a0.w - b0.w; p[0] += dx * dx;
            dx = a1.x - b1.x; p[1]  = dx * dx;
            dx = a1.y - b1.y; p[1] += dx * dx;
            dx = a1.z - b1.z; p[1] += dx * dx;
            dx = a1.w - b1.w; p[1] += dx * dx;
            dx = a2.x - b2.x; p[2]  = dx * dx;
            dx = a2.y - b2.y; p[2] += dx * dx;
            dx = a2.z - b2.z; p[2] += dx * dx;
            dx = a2.w - b2.w; p[2] += dx * dx;
            dx = a3.x - b3.x; p[3]  = dx * dx;
            dx = a3.y - b3.y; p[3] += dx * dx;
            dx = a3.z - b3.z; p[3] += dx * dx;
            dx = a3.w - b3.w; p[3] += dx * dx;
            dx = a4.x - b4.x; p[4]  = dx * dx;
            dx = a4.y - b4.y; p[4] += dx * dx;
            dx = a4.z - b4.z; p[4] += dx * dx;
            dx = a4.w - b4.w; p[4] += dx * dx;
            dx = a5.x - b5.x; p[5]  = dx * dx;
            dx = a5.y - b5.y; p[5] += dx * dx;
            dx = a5.z - b5.z; p[5] += dx * dx;
            dx = a5.w - b5.w; p[5] += dx * dx;
            dx = a6.x - b6.x; p[6]  = dx * dx;
            dx = a6.y - b6.y; p[6] += dx * dx;
            dx = a6.z - b6.z; p[6] += dx * dx;
            dx = a6.w - b6.w; p[6] += dx * dx;
            dx = a7.x - b7.x; p[7]  = dx * dx;
            dx = a7.y - b7.y; p[7] += dx * dx;
            dx = a7.z - b7.z; p[7] += dx * dx;
            dx = a7.w - b7.w; p[7] += dx * dx;

            // butterfly within the 16-lane quarter -> all lanes hold full sums
#pragma unroll
            for (int off = 1; off < 16; off <<= 1) {
#pragma unroll
                for (int t = 0; t < NEXP; ++t) p[t] += __shfl_xor(p[t], off);
            }

            float gp[NEXP] = { gs0.x * gd0.x, gs0.y * gd0.y, gs0.z * gd0.z, gs0.w * gd0.w,
                               gs1.x * gd1.x, gs1.y * gd1.y, gs1.z * gd1.z, gs1.w * gd1.w };
            float m = gp[0];
#pragma unroll
            for (int t = 1; t < NEXP; ++t) m = fmaxf(m, gp[t]);
            float se = 0.0f;
#pragma unroll
            for (int t = 0; t < NEXP; ++t) { gp[t] = expf(gp[t] - m); se += gp[t]; }
            float dsum = 0.0f;
#pragma unroll
            for (int t = 0; t < NEXP; ++t) dsum += p[t] * gp[t];

            lsum += fabsf((dsum / se) / dv - 1.0f);
        }
    }
    // all 16 lanes of a quarter hold the same lsum; xor 16 then 32 sums quarters
    lsum += __shfl_xor(lsum, 16);
    lsum += __shfl_xor(lsum, 32);
    if (lane == 0) atomicAdd(loss, lsum / (float)E2);
}

// ---------------- launch ----------------
extern "C" void kernel_launch(void* const* d_in, const int* in_sizes, int n_in,
                              void* d_out, int out_size, void* d_ws, size_t ws_size,
                              hipStream_t stream)
{
    const float* x0   = (const float*)d_in[0];
    const float* x1   = (const float*)d_in[1];
    const float* W1   = (const float*)d_in[2];
    const float* b1   = (const float*)d_in[3];
    const float* W2   = (const float*)d_in[4];
    const float* b2   = (const float*)d_in[5];
    const float* Wc   = (const float*)d_in[6];
    const float* bc   = (const float*)d_in[7];
    const float* emb  = (const float*)d_in[8];
    const float* dis  = (const float*)d_in[9];
    const int*   ei0  = (const int*)d_in[10];
    const int*   ei1  = (const int*)d_in[11];
    const int*   bat0 = (const int*)d_in[12];
    const int*   bat1 = (const int*)d_in[13];
    const int*   ei2  = (const int*)d_in[14];

    const int N  = in_sizes[0] / IN_F;
    const int E  = in_sizes[10] / 2;
    const int B  = in_sizes[8] / (NEXP * EMB);
    const int E2 = in_sizes[14] / 2;
    const int n2 = 2 * N;
    const int nk = 4 * B;                          // sort keys
    const int quarter = (B + 3) / 4;

    float* gate_out = (float*)d_out;               // B*NEXP
    float* loss_out = gate_out + (size_t)B * NEXP; // 1

    // workspace layout (floats)
    float* ws      = (float*)d_ws;
    float* dinv    = ws;                           // 2N
    float* Ys      = dinv + n2;                    // 2N*32 f32 region (P final; bf16 Ysh aliases)
    float* Zs      = Ys + (size_t)n2 * OUT_F;      // 2N*32 f32 region (bf16 Zsh aliases)
    float* sdsum   = Zs + (size_t)n2 * OUT_F;      // 2N
    float* pooled  = sdsum + n2;                   // 2B*32
    float* cnt     = pooled + (size_t)2 * B * OUT_F; // 2B (contiguous after pooled)
    float* W12     = cnt + 2 * B;                  // 64*32
    float* c1      = W12 + IN_F * OUT_F;           // 32
    float* disD    = c1 + OUT_F;                   // E2
    int*   iws     = (int*)(disD + E2);
    int*   counts  = iws;                          // 2N     (zeroed together with histK)
    int*   histK   = counts + n2;                  // 4B     (adjacent to counts)
    int*   offsets = histK + nk;                   // 2N+1
    int*   cursor  = offsets + n2 + 1;             // 2N
    int*   csr_src = cursor + n2;                  // 2E
    int*   lexcl   = csr_src + 2 * E;              // 2N
    int*   partials= lexcl + n2;                   // <=1024
    int*   lexclK  = partials + 1024;              // 4B
    int*   partialsK = lexclK + nk;                // <=1024 (16 used)
    int*   offK    = partialsK + 1024;             // 4B+1
    int*   curK    = offK + nk + 1;                // 4B
    int*   dD      = curK + nk;                    // E2

    unsigned short* Ysh = (unsigned short*)Ys;     // bf16 Ys (first half of region)
    unsigned short* Zsh = (unsigned short*)Zs;     // bf16 Zs
    float* P = Ys;                                 // final f32 h2 (Ysh dead by then)

    const int TB = 256;
    const int zgrid = 512;
    const int NB2 = (n2 + 1023) / 1024;            // scan blocks over 2N
    const int NBK = (nk + 1023) / 1024;            // scan blocks over 4B keys

    // W12 = W1@W2, c1 = b1@W2 (once)
    w12_kernel<<<1, 1024, 0, stream>>>(W1, W2, b1, W12, c1);

    // ---- fused CSR build over both graphs ----
    zero_i32_kernel<<<zgrid, TB, 0, stream>>>(counts, (long long)n2 + nk);  // counts+histK
    hist2_kernel<<<(2 * E + TB - 1) / TB, TB, 0, stream>>>(ei0, ei1, counts, E, N);
    scan1_kernel<<<NB2, 1024, 0, stream>>>(counts, lexcl, partials, n2);
    scan2_kernel<<<1, 1024, 0, stream>>>(partials, NB2);
    scan3_kernel<<<(n2 + TB - 1) / TB, TB, 0, stream>>>(lexcl, partials, counts,
                                                        offsets, cursor, dinv, n2, 2 * E);
    scatter2_shard_kernel<<<1024, TB, 0, stream>>>(ei0, ei1, cursor, csr_src, E, N, n2);

    // ---- distortion edge sort by key (qd, s) ----
    histK_kernel<<<(E2 + TB - 1) / TB, TB, 0, stream>>>(ei2, ei2 + E2, histK, E2, B, quarter);
    scan1_kernel<<<NBK, 1024, 0, stream>>>(histK, lexclK, partialsK, nk);
    scan2_kernel<<<1, 1024, 0, stream>>>(partialsK, NBK);
    combineK_kernel<<<(nk + TB - 1) / TB, TB, 0, stream>>>(lexclK, partialsK, offK, curK, nk, E2);
    scatterK_kernel<<<(E2 + TB - 1) / TB, TB, 0, stream>>>(ei2, ei2 + E2, dis,
                                                           curK, dD, disD, E2, B, quarter);

    // ---- encoder: Ys(bf16) = (X@W12)*dinv ; two bf16-operand agg passes ----
    gemm_ys2_kernel<<<(n2 + 7) / 8, 256, 0, stream>>>(x0, x1, W12, dinv, Ysh, N, n2);
    csr_agg32_kernel<0><<<(n2 + 7) / 8, TB, 0, stream>>>(csr_src, offsets, Ysh, dinv,
                                                         sdsum, nullptr, nullptr,
                                                         Zsh, nullptr, n2);
    csr_agg32_kernel<1><<<(n2 + 7) / 8, TB, 0, stream>>>(csr_src, offsets, Zsh, dinv,
                                                         sdsum, c1, b2,
                                                         nullptr, P, n2);

    // ---- mean pool (both graphs): zero pooled+cnt in ONE call (contiguous) ----
    zero_f32_kernel<<<zgrid, TB, 0, stream>>>(pooled, (long long)2 * B * OUT_F + 2 * B);
    pool_sum2_kernel<<<((n2 * 32) + TB - 1) / TB, TB, 0, stream>>>(P, bat0, bat1,
                                                                   pooled, cnt, N, n2, B);

    // ---- gate (pool-div fused, zeroes loss_out) ----
    gate_kernel<<<(B + TB - 1) / TB, TB, 0, stream>>>(pooled, cnt, Wc, bc,
                                                      gate_out, loss_out, B);

    // ---- distortion loss (XCD-sharded, quarter-wave per edge, 1024 blocks) ----
    distortion6_kernel<<<1024, TB, 0, stream>>>(emb, gate_out, offK, dD, disD,
                                                loss_out, B, E2);
}